// Round 1
// baseline (6935.439 us; speedup 1.0000x reference)
//
#include <hip/hip_runtime.h>
#include <math.h>

#define NNODES 100000
#define NEDGES 20000
#define NNZ_   2000000
#define FDIM   128
#define BN_EPS 1e-5f

__device__ __forceinline__ float sigmoidf_(float x) {
    return 1.0f / (1.0f + __expf(-x));
}

// ---- transpose W[128,K] (row-major) -> WT[K,128] (k-major) ----
__global__ __launch_bounds__(256) void transpose_w(const float* __restrict__ W,
                                                   float* __restrict__ WT, int K) {
    int idx = blockIdx.x * blockDim.x + threadIdx.x;
    if (idx >= K * FDIM) return;
    int k = idx >> 7;      // /128
    int c = idx & 127;
    WT[idx] = W[c * K + k];
}

// ---- out[M,128] = sigmoid(cat(A1,A2)[M,K] @ W[128,K]^T + b) ----
// WT is [K,128] k-major. K=128 (A2 unused) or K=256 (k>=128 from A2).
template<int K>
__global__ __launch_bounds__(256, 2) void gemm_sig(
    const float* __restrict__ A1, const float* __restrict__ A2,
    const float* __restrict__ WT, const float* __restrict__ bias,
    float* __restrict__ out)
{
    constexpr int BK = 64;
    constexpr int TM = 32;
    __shared__ float As[TM][BK + 4];   // +4 keeps float4 alignment, breaks pow2 stride
    __shared__ float Ws[BK][FDIM];     // k-major: inner reads conflict-free
    const int tid  = threadIdx.x;
    const int row0 = blockIdx.x * TM;
    const int tcol = tid & 31;   // 32 col-groups of 4
    const int trow = tid >> 5;   // 8 row-groups of 4
    float acc[4][4] = {};

    for (int kk = 0; kk < K; kk += BK) {
        const float* Asrc = (kk < FDIM) ? A1 : A2;
        const int koff    = (kk < FDIM) ? kk : kk - FDIM;
        // stage A tile: 32 rows x 64 k = 512 float4, 2 per thread
        #pragma unroll
        for (int i = 0; i < 2; i++) {
            int l = tid + i * 256;
            int r = l >> 4, j = l & 15;
            float4 v = *(const float4*)(Asrc + (size_t)(row0 + r) * FDIM + koff + j * 4);
            *(float4*)&As[r][j * 4] = v;
        }
        // stage W tile: 64 k x 128 c = 2048 float4, 8 per thread (straight copy)
        #pragma unroll
        for (int i = 0; i < 8; i++) {
            int l = tid + i * 256;
            int k = l >> 5, j = l & 31;
            float4 v = *(const float4*)(WT + (size_t)(kk + k) * FDIM + j * 4);
            *(float4*)&Ws[k][j * 4] = v;
        }
        __syncthreads();
        #pragma unroll
        for (int k = 0; k < BK; k += 4) {
            float4 a[4];
            #pragma unroll
            for (int r = 0; r < 4; r++)
                a[r] = *(const float4*)&As[trow * 4 + r][k];   // broadcast within half-wave
            #pragma unroll
            for (int kq = 0; kq < 4; kq++) {
                float4 w = *(const float4*)&Ws[k + kq][tcol * 4]; // consecutive lanes -> consecutive addr
                #pragma unroll
                for (int r = 0; r < 4; r++) {
                    float av = (kq == 0) ? a[r].x : (kq == 1) ? a[r].y
                             : (kq == 2) ? a[r].z : a[r].w;
                    acc[r][0] += av * w.x;
                    acc[r][1] += av * w.y;
                    acc[r][2] += av * w.z;
                    acc[r][3] += av * w.w;
                }
            }
        }
        __syncthreads();
    }
    float4 bv = *(const float4*)(bias + tcol * 4);
    #pragma unroll
    for (int r = 0; r < 4; r++) {
        int row = row0 + trow * 4 + r;
        float4 o;
        o.x = sigmoidf_(acc[r][0] + bv.x);
        o.y = sigmoidf_(acc[r][1] + bv.y);
        o.z = sigmoidf_(acc[r][2] + bv.z);
        o.w = sigmoidf_(acc[r][3] + bv.w);
        *(float4*)(out + (size_t)row * FDIM + tcol * 4) = o;
    }
}

// ---- dst[sidx[p],:] += table[gidx[p],:] over 2M pairs; 32 lanes/pair ----
__global__ __launch_bounds__(256) void scatter_add(
    const float* __restrict__ table, const int* __restrict__ gidx,
    const int* __restrict__ sidx, float* __restrict__ dst, int npairs)
{
    int gid = blockIdx.x * blockDim.x + threadIdx.x;
    int p = gid >> 5;
    if (p >= npairs) return;
    int q = (gid & 31) * 4;
    int s = gidx[p];
    int d = sidx[p];
    float4 v = *(const float4*)(table + (size_t)s * FDIM + q);
    float* o = dst + (size_t)d * FDIM + q;
    unsafeAtomicAdd(o + 0, v.x);   // hardware global_atomic_add_f32
    unsafeAtomicAdd(o + 1, v.y);
    unsafeAtomicAdd(o + 2, v.z);
    unsafeAtomicAdd(o + 3, v.w);
}

// ---- out = sigmoid(bn(x) + agg), elementwise over rows*128 ----
__global__ __launch_bounds__(256) void finalize(
    const float* __restrict__ x, const float* __restrict__ agg,
    const float* __restrict__ gamma, const float* __restrict__ beta,
    const float* __restrict__ mean, const float* __restrict__ var,
    float* __restrict__ out, int nquads)
{
    int gid = blockIdx.x * blockDim.x + threadIdx.x;
    if (gid >= nquads) return;
    int q = (gid & 31) * 4;   // feature offset (row-major, 32 quads per row)
    float4 xv = *(const float4*)(x + (size_t)gid * 4);
    float4 av = *(const float4*)(agg + (size_t)gid * 4);
    float4 g = *(const float4*)(gamma + q);
    float4 b = *(const float4*)(beta + q);
    float4 m = *(const float4*)(mean + q);
    float4 vv = *(const float4*)(var + q);
    float4 o;
    o.x = sigmoidf_((xv.x - m.x) * (g.x * rsqrtf(vv.x + BN_EPS)) + b.x + av.x);
    o.y = sigmoidf_((xv.y - m.y) * (g.y * rsqrtf(vv.y + BN_EPS)) + b.y + av.y);
    o.z = sigmoidf_((xv.z - m.z) * (g.z * rsqrtf(vv.z + BN_EPS)) + b.z + av.z);
    o.w = sigmoidf_((xv.w - m.w) * (g.w * rsqrtf(vv.w + BN_EPS)) + b.w + av.w);
    *(float4*)(out + (size_t)gid * 4) = o;
}

extern "C" void kernel_launch(void* const* d_in, const int* in_sizes, int n_in,
                              void* d_out, int out_size, void* d_ws, size_t ws_size,
                              hipStream_t stream)
{
    const float* x0       = (const float*)d_in[0];
    const float* x1       = (const float*)d_in[1];
    const int*   node_idx = (const int*)d_in[2];
    const int*   edge_idx = (const int*)d_in[3];
    const float* W_nh     = (const float*)d_in[4];
    const float* b_nh     = (const float*)d_in[5];
    const float* W_en     = (const float*)d_in[6];
    const float* b_en     = (const float*)d_in[7];
    const float* bn0g = (const float*)d_in[8];
    const float* bn0b = (const float*)d_in[9];
    const float* bn0m = (const float*)d_in[10];
    const float* bn0v = (const float*)d_in[11];
    const float* bn1g = (const float*)d_in[12];
    const float* bn1b = (const float*)d_in[13];
    const float* bn1m = (const float*)d_in[14];
    const float* bn1v = (const float*)d_in[15];

    float* ws = (float*)d_ws;
    float* A    = ws;                                   // node_messages [100000,128]
    float* B    = A + (size_t)NNODES * FDIM;            // node_msg_agg  [20000,128]
    float* C    = B + (size_t)NEDGES * FDIM;            // he_msg_agg    [100000,128]
    float* D    = C + (size_t)NNODES * FDIM;            // he_messages   [20000,128]
    float* WTnh = D + (size_t)NEDGES * FDIM;            // [128,128] k-major
    float* WTen = WTnh + FDIM * FDIM;                   // [256,128] k-major

    // zero the two aggregation buffers (B and C are adjacent)
    hipMemsetAsync(B, 0, (size_t)(NEDGES + NNODES) * FDIM * sizeof(float), stream);

    transpose_w<<<(FDIM * FDIM + 255) / 256, 256, 0, stream>>>(W_nh, WTnh, FDIM);
    transpose_w<<<(2 * FDIM * FDIM + 255) / 256, 256, 0, stream>>>(W_en, WTen, 2 * FDIM);

    // node -> hyperedge messenger
    gemm_sig<128><<<NNODES / 32, 256, 0, stream>>>(x0, nullptr, WTnh, b_nh, A);
    scatter_add<<<(NNZ_ * 32) / 256, 256, 0, stream>>>(A, node_idx, edge_idx, B, NNZ_);

    // hyperedge -> node messenger
    gemm_sig<256><<<NEDGES / 32, 256, 0, stream>>>(x1, B, WTen, b_en, D);
    scatter_add<<<(NNZ_ * 32) / 256, 256, 0, stream>>>(D, edge_idx, node_idx, C, NNZ_);

    // updates
    float* out0 = (float*)d_out;
    float* out1 = out0 + (size_t)NNODES * FDIM;
    finalize<<<(NNODES * 32 + 255) / 256, 256, 0, stream>>>(x0, C, bn0g, bn0b, bn0m, bn0v, out0, NNODES * 32);
    finalize<<<(NEDGES * 32 + 255) / 256, 256, 0, stream>>>(x1, B, bn1g, bn1b, bn1m, bn1v, out1, NEDGES * 32);
}

// Round 2
// 1287.747 us; speedup vs baseline: 5.3857x; 5.3857x over previous
//
#include <hip/hip_runtime.h>
#include <math.h>

#define NNODES 100000
#define NEDGES 20000
#define NNZ_   2000000
#define FDIM   128
#define BN_EPS 1e-5f

__device__ __forceinline__ float sigmoidf_(float x) {
    return 1.0f / (1.0f + __expf(-x));
}
__device__ __forceinline__ float4 f4add(float4 a, float4 b) {
    a.x += b.x; a.y += b.y; a.z += b.z; a.w += b.w; return a;
}

// ---- transpose W[128,K] (row-major) -> WT[K,128] (k-major) ----
__global__ __launch_bounds__(256) void transpose_w(const float* __restrict__ W,
                                                   float* __restrict__ WT, int K) {
    int idx = blockIdx.x * blockDim.x + threadIdx.x;
    if (idx >= K * FDIM) return;
    int k = idx >> 7;
    int c = idx & 127;
    WT[idx] = W[c * K + k];
}

// ---- out[M,128] = sigmoid(cat(A1,A2)[M,K] @ W[128,K]^T + b) ----
template<int K>
__global__ __launch_bounds__(256, 2) void gemm_sig(
    const float* __restrict__ A1, const float* __restrict__ A2,
    const float* __restrict__ WT, const float* __restrict__ bias,
    float* __restrict__ out)
{
    constexpr int BK = 64;
    constexpr int TM = 32;
    __shared__ float As[TM][BK + 4];
    __shared__ float Ws[BK][FDIM];
    const int tid  = threadIdx.x;
    const int row0 = blockIdx.x * TM;
    const int tcol = tid & 31;
    const int trow = tid >> 5;
    float acc[4][4] = {};

    for (int kk = 0; kk < K; kk += BK) {
        const float* Asrc = (kk < FDIM) ? A1 : A2;
        const int koff    = (kk < FDIM) ? kk : kk - FDIM;
        #pragma unroll
        for (int i = 0; i < 2; i++) {
            int l = tid + i * 256;
            int r = l >> 4, j = l & 15;
            float4 v = *(const float4*)(Asrc + (size_t)(row0 + r) * FDIM + koff + j * 4);
            *(float4*)&As[r][j * 4] = v;
        }
        #pragma unroll
        for (int i = 0; i < 8; i++) {
            int l = tid + i * 256;
            int k = l >> 5, j = l & 31;
            float4 v = *(const float4*)(WT + (size_t)(kk + k) * FDIM + j * 4);
            *(float4*)&Ws[k][j * 4] = v;
        }
        __syncthreads();
        #pragma unroll
        for (int k = 0; k < BK; k += 4) {
            float4 a[4];
            #pragma unroll
            for (int r = 0; r < 4; r++)
                a[r] = *(const float4*)&As[trow * 4 + r][k];
            #pragma unroll
            for (int kq = 0; kq < 4; kq++) {
                float4 w = *(const float4*)&Ws[k + kq][tcol * 4];
                #pragma unroll
                for (int r = 0; r < 4; r++) {
                    float av = (kq == 0) ? a[r].x : (kq == 1) ? a[r].y
                             : (kq == 2) ? a[r].z : a[r].w;
                    acc[r][0] += av * w.x;
                    acc[r][1] += av * w.y;
                    acc[r][2] += av * w.z;
                    acc[r][3] += av * w.w;
                }
            }
        }
        __syncthreads();
    }
    float4 bv = *(const float4*)(bias + tcol * 4);
    #pragma unroll
    for (int r = 0; r < 4; r++) {
        int row = row0 + trow * 4 + r;
        float4 o;
        o.x = sigmoidf_(acc[r][0] + bv.x);
        o.y = sigmoidf_(acc[r][1] + bv.y);
        o.z = sigmoidf_(acc[r][2] + bv.z);
        o.w = sigmoidf_(acc[r][3] + bv.w);
        *(float4*)(out + (size_t)row * FDIM + tcol * 4) = o;
    }
}

// ---- CSR build: count, scan, fill ----
__global__ __launch_bounds__(256) void count_pairs(
    const int* __restrict__ ni, const int* __restrict__ ei,
    int* __restrict__ cnt_n, int* __restrict__ cnt_e)
{
    int p = blockIdx.x * blockDim.x + threadIdx.x;
    if (p >= NNZ_) return;
    atomicAdd(&cnt_e[ei[p]], 1);
    atomicAdd(&cnt_n[ni[p]], 1);
}

// single-block exclusive scan; cnt becomes the fill cursor (== off)
__global__ __launch_bounds__(1024) void excl_scan(int* __restrict__ cnt,
                                                  int* __restrict__ off, int n)
{
    __shared__ int sh[1024];
    int t = threadIdx.x;
    int chunk = (n + 1023) / 1024;
    int base = t * chunk;
    int lim = min(base + chunk, n);
    int sum = 0;
    for (int i = base; i < lim; i++) sum += cnt[i];
    sh[t] = sum;
    __syncthreads();
    for (int d = 1; d < 1024; d <<= 1) {
        int v = (t >= d) ? sh[t - d] : 0;
        __syncthreads();
        sh[t] += v;
        __syncthreads();
    }
    int run = sh[t] - sum;   // exclusive prefix of this thread's chunk
    for (int i = base; i < lim; i++) {
        int c = cnt[i];
        off[i] = run;
        cnt[i] = run;        // cursor for fill phase
        run += c;
    }
    if (t == 1023) off[n] = sh[1023];
}

__global__ __launch_bounds__(256) void fill_csr(
    const int* __restrict__ ni, const int* __restrict__ ei,
    int* __restrict__ cur_n, int* __restrict__ cur_e,
    int* __restrict__ csr_n, int* __restrict__ csr_e)
{
    int p = blockIdx.x * blockDim.x + threadIdx.x;
    if (p >= NNZ_) return;
    int n = ni[p], e = ei[p];
    int pe = atomicAdd(&cur_e[e], 1);
    csr_e[pe] = n;                    // gather-source row for edge segment
    int pn = atomicAdd(&cur_n[n], 1);
    csr_n[pn] = e;                    // gather-source row for node segment
}

// ---- segmented sum (pull) + optional fused BN/sigmoid finalize ----
// 32 lanes per segment; lane handles 4 consecutive features (float4).
__global__ __launch_bounds__(256) void seg_sum_fin(
    const float* __restrict__ table, const int* __restrict__ csr,
    const int* __restrict__ off, const float* __restrict__ x,
    const float* __restrict__ g, const float* __restrict__ bb,
    const float* __restrict__ mm, const float* __restrict__ vv,
    float* __restrict__ agg_out, float* __restrict__ fin_out, int nseg)
{
    int gid = blockIdx.x * blockDim.x + threadIdx.x;
    int seg = gid >> 5;
    if (seg >= nseg) return;
    int q = (gid & 31) * 4;
    int i0 = off[seg], i1 = off[seg + 1];
    float4 acc = make_float4(0.f, 0.f, 0.f, 0.f);
    int i = i0;
    for (; i + 1 < i1; i += 2) {       // 2-way unroll: two gathers in flight
        int r0 = csr[i], r1 = csr[i + 1];
        float4 a0 = *(const float4*)(table + (size_t)r0 * FDIM + q);
        float4 a1 = *(const float4*)(table + (size_t)r1 * FDIM + q);
        acc = f4add(acc, f4add(a0, a1));
    }
    if (i < i1) {
        int r = csr[i];
        acc = f4add(acc, *(const float4*)(table + (size_t)r * FDIM + q));
    }
    if (agg_out)
        *(float4*)(agg_out + (size_t)seg * FDIM + q) = acc;
    if (fin_out) {
        float4 xv = *(const float4*)(x + (size_t)seg * FDIM + q);
        float4 gg = *(const float4*)(g + q);
        float4 bt = *(const float4*)(bb + q);
        float4 mn = *(const float4*)(mm + q);
        float4 vr = *(const float4*)(vv + q);
        float4 o;
        o.x = sigmoidf_((xv.x - mn.x) * (gg.x * rsqrtf(vr.x + BN_EPS)) + bt.x + acc.x);
        o.y = sigmoidf_((xv.y - mn.y) * (gg.y * rsqrtf(vr.y + BN_EPS)) + bt.y + acc.y);
        o.z = sigmoidf_((xv.z - mn.z) * (gg.z * rsqrtf(vr.z + BN_EPS)) + bt.z + acc.z);
        o.w = sigmoidf_((xv.w - mn.w) * (gg.w * rsqrtf(vr.w + BN_EPS)) + bt.w + acc.w);
        *(float4*)(fin_out + (size_t)seg * FDIM + q) = o;
    }
}

extern "C" void kernel_launch(void* const* d_in, const int* in_sizes, int n_in,
                              void* d_out, int out_size, void* d_ws, size_t ws_size,
                              hipStream_t stream)
{
    const float* x0       = (const float*)d_in[0];
    const float* x1       = (const float*)d_in[1];
    const int*   node_idx = (const int*)d_in[2];
    const int*   edge_idx = (const int*)d_in[3];
    const float* W_nh     = (const float*)d_in[4];
    const float* b_nh     = (const float*)d_in[5];
    const float* W_en     = (const float*)d_in[6];
    const float* b_en     = (const float*)d_in[7];
    const float* bn0g = (const float*)d_in[8];
    const float* bn0b = (const float*)d_in[9];
    const float* bn0m = (const float*)d_in[10];
    const float* bn0v = (const float*)d_in[11];
    const float* bn1g = (const float*)d_in[12];
    const float* bn1b = (const float*)d_in[13];
    const float* bn1m = (const float*)d_in[14];
    const float* bn1v = (const float*)d_in[15];

    float* ws = (float*)d_ws;
    float* A    = ws;                           // node_messages [100000,128]
    float* B    = A + (size_t)NNODES * FDIM;    // node_msg_agg  [20000,128]
    float* D    = B + (size_t)NEDGES * FDIM;    // he_messages   [20000,128]
    float* WTnh = D + (size_t)NEDGES * FDIM;    // [128,128]
    float* WTen = WTnh + FDIM * FDIM;           // [256,128]
    int* ip    = (int*)(WTen + 2 * FDIM * FDIM);
    int* cnt_e = ip;                    // 20000  (becomes fill cursor)
    int* cnt_n = cnt_e + NEDGES;        // 100000 (becomes fill cursor)
    int* off_e = cnt_n + NNODES;        // 20001 (pad to 20004)
    int* off_n = off_e + 20004;         // 100001 (pad to 100004)
    int* csr_e = off_n + 100004;        // 2M: node row ids grouped by edge
    int* csr_n = csr_e + NNZ_;          // 2M: edge row ids grouped by node

    // zero both histograms (contiguous)
    hipMemsetAsync(cnt_e, 0, (size_t)(NEDGES + NNODES) * sizeof(int), stream);

    // CSR build
    count_pairs<<<(NNZ_ + 255) / 256, 256, 0, stream>>>(node_idx, edge_idx, cnt_n, cnt_e);
    excl_scan<<<1, 1024, 0, stream>>>(cnt_e, off_e, NEDGES);
    excl_scan<<<1, 1024, 0, stream>>>(cnt_n, off_n, NNODES);
    fill_csr<<<(NNZ_ + 255) / 256, 256, 0, stream>>>(node_idx, edge_idx,
                                                     cnt_n, cnt_e, csr_n, csr_e);

    // weight transposes
    transpose_w<<<(FDIM * FDIM + 255) / 256, 256, 0, stream>>>(W_nh, WTnh, FDIM);
    transpose_w<<<(2 * FDIM * FDIM + 255) / 256, 256, 0, stream>>>(W_en, WTen, 2 * FDIM);

    float* out0 = (float*)d_out;
    float* out1 = out0 + (size_t)NNODES * FDIM;

    // node -> hyperedge: GEMM1 then pull-aggregate onto edges (+ fused x1_out)
    gemm_sig<128><<<NNODES / 32, 256, 0, stream>>>(x0, nullptr, WTnh, b_nh, A);
    seg_sum_fin<<<(NEDGES * 32 + 255) / 256, 256, 0, stream>>>(
        A, csr_e, off_e, x1, bn1g, bn1b, bn1m, bn1v, B, out1, NEDGES);

    // hyperedge -> node: GEMM2 then pull-aggregate onto nodes (+ fused x0_out)
    gemm_sig<256><<<NEDGES / 32, 256, 0, stream>>>(x1, B, WTen, b_en, D);
    seg_sum_fin<<<(NNODES * 32 + 255) / 256, 256, 0, stream>>>(
        D, csr_n, off_n, x0, bn0g, bn0b, bn0m, bn0v, nullptr, out0, NNODES);
}

// Round 3
// 845.675 us; speedup vs baseline: 8.2011x; 1.5227x over previous
//
#include <hip/hip_runtime.h>
#include <math.h>

#define NNODES 100000
#define NEDGES 20000
#define NNZ_   2000000
#define FDIM   128
#define BN_EPS 1e-5f

#define NCHUNK 32
#define CHSZ   (NNZ_ / NCHUNK)   // 62500
#define RANGE  16000             // bins per LDS pass (64000 B LDS)

__device__ __forceinline__ float sigmoidf_(float x) {
    return 1.0f / (1.0f + __expf(-x));
}
__device__ __forceinline__ float4 f4add(float4 a, float4 b) {
    a.x += b.x; a.y += b.y; a.z += b.z; a.w += b.w; return a;
}

// ---- transpose W[128,K] (row-major) -> WT[K,128] (k-major) ----
__global__ __launch_bounds__(256) void transpose_w(const float* __restrict__ W,
                                                   float* __restrict__ WT, int K) {
    int idx = blockIdx.x * blockDim.x + threadIdx.x;
    if (idx >= K * FDIM) return;
    int k = idx >> 7;
    int c = idx & 127;
    WT[idx] = W[c * K + k];
}

// ---- out[M,128] = sigmoid(cat(A1,A2)[M,K] @ W[128,K]^T + b) ----
template<int K>
__global__ __launch_bounds__(256, 2) void gemm_sig(
    const float* __restrict__ A1, const float* __restrict__ A2,
    const float* __restrict__ WT, const float* __restrict__ bias,
    float* __restrict__ out)
{
    constexpr int BK = 64;
    constexpr int TM = 32;
    __shared__ float As[TM][BK + 4];
    __shared__ float Ws[BK][FDIM];
    const int tid  = threadIdx.x;
    const int row0 = blockIdx.x * TM;
    const int tcol = tid & 31;
    const int trow = tid >> 5;
    float acc[4][4] = {};

    for (int kk = 0; kk < K; kk += BK) {
        const float* Asrc = (kk < FDIM) ? A1 : A2;
        const int koff    = (kk < FDIM) ? kk : kk - FDIM;
        #pragma unroll
        for (int i = 0; i < 2; i++) {
            int l = tid + i * 256;
            int r = l >> 4, j = l & 15;
            float4 v = *(const float4*)(Asrc + (size_t)(row0 + r) * FDIM + koff + j * 4);
            *(float4*)&As[r][j * 4] = v;
        }
        #pragma unroll
        for (int i = 0; i < 8; i++) {
            int l = tid + i * 256;
            int k = l >> 5, j = l & 31;
            float4 v = *(const float4*)(WT + (size_t)(kk + k) * FDIM + j * 4);
            *(float4*)&Ws[k][j * 4] = v;
        }
        __syncthreads();
        #pragma unroll
        for (int k = 0; k < BK; k += 4) {
            float4 a[4];
            #pragma unroll
            for (int r = 0; r < 4; r++)
                a[r] = *(const float4*)&As[trow * 4 + r][k];
            #pragma unroll
            for (int kq = 0; kq < 4; kq++) {
                float4 w = *(const float4*)&Ws[k + kq][tcol * 4];
                #pragma unroll
                for (int r = 0; r < 4; r++) {
                    float av = (kq == 0) ? a[r].x : (kq == 1) ? a[r].y
                             : (kq == 2) ? a[r].z : a[r].w;
                    acc[r][0] += av * w.x;
                    acc[r][1] += av * w.y;
                    acc[r][2] += av * w.z;
                    acc[r][3] += av * w.w;
                }
            }
        }
        __syncthreads();
    }
    float4 bv = *(const float4*)(bias + tcol * 4);
    #pragma unroll
    for (int r = 0; r < 4; r++) {
        int row = row0 + trow * 4 + r;
        float4 o;
        o.x = sigmoidf_(acc[r][0] + bv.x);
        o.y = sigmoidf_(acc[r][1] + bv.y);
        o.z = sigmoidf_(acc[r][2] + bv.z);
        o.w = sigmoidf_(acc[r][3] + bv.w);
        *(float4*)(out + (size_t)row * FDIM + tcol * 4) = o;
    }
}

// ---- CSR build, atomic-free at device scope ----
// per-chunk histogram for bins [by*RANGE, by*RANGE+rsz): LDS atomics + coalesced flush
__global__ __launch_bounds__(1024) void hist_range(
    const int* __restrict__ key, int* __restrict__ bh, int nbins)
{
    __shared__ int sh[RANGE];
    const int c   = blockIdx.x;
    const int rlo = blockIdx.y * RANGE;
    const int rsz = min(RANGE, nbins - rlo);
    const int tid = threadIdx.x;
    for (int j = tid; j < rsz; j += 1024) sh[j] = 0;
    __syncthreads();
    const int end = (c + 1) * CHSZ;
    for (int i = c * CHSZ + tid; i < end; i += 1024) {
        unsigned v = (unsigned)(key[i] - rlo);
        if (v < (unsigned)rsz) atomicAdd(&sh[v], 1);
    }
    __syncthreads();
    for (int j = tid; j < rsz; j += 1024)
        bh[(size_t)c * nbins + rlo + j] = sh[j];
}

// cnt[bin] = sum over chunks of bh[c][bin]
__global__ __launch_bounds__(256) void colsum(
    const int* __restrict__ bh, int* __restrict__ cnt, int nbins)
{
    int bin = blockIdx.x * blockDim.x + threadIdx.x;
    if (bin >= nbins) return;
    int s = 0;
    #pragma unroll 4
    for (int c = 0; c < NCHUNK; c++) s += bh[(size_t)c * nbins + bin];
    cnt[bin] = s;
}

// single-block exclusive scan: cnt -> off
__global__ __launch_bounds__(1024) void excl_scan(int* __restrict__ cnt,
                                                  int* __restrict__ off, int n)
{
    __shared__ int sh[1024];
    int t = threadIdx.x;
    int chunk = (n + 1023) / 1024;
    int base = t * chunk;
    int lim = min(base + chunk, n);
    int sum = 0;
    for (int i = base; i < lim; i++) sum += cnt[i];
    sh[t] = sum;
    __syncthreads();
    for (int d = 1; d < 1024; d <<= 1) {
        int v = (t >= d) ? sh[t - d] : 0;
        __syncthreads();
        sh[t] += v;
        __syncthreads();
    }
    int run = sh[t] - sum;
    for (int i = base; i < lim; i++) {
        int c = cnt[i];
        off[i] = run;
        run += c;
    }
    if (t == 1023) off[n] = sh[1023];
}

// bh[c][bin] := off[bin] + prefix over chunks (per-(chunk,bin) start positions)
__global__ __launch_bounds__(256) void rebase(
    int* __restrict__ bh, const int* __restrict__ off, int nbins)
{
    int bin = blockIdx.x * blockDim.x + threadIdx.x;
    if (bin >= nbins) return;
    int run = off[bin];
    for (int c = 0; c < NCHUNK; c++) {
        size_t p = (size_t)c * nbins + bin;
        int old = bh[p];
        bh[p] = run;
        run += old;
    }
}

// fill: LDS cursors (loaded from bh), LDS fetch-add rank, plain scattered store
__global__ __launch_bounds__(1024) void fill_range(
    const int* __restrict__ key, const int* __restrict__ payload,
    const int* __restrict__ bh, int* __restrict__ csr, int nbins)
{
    __shared__ int sh[RANGE];
    const int c   = blockIdx.x;
    const int rlo = blockIdx.y * RANGE;
    const int rsz = min(RANGE, nbins - rlo);
    const int tid = threadIdx.x;
    for (int j = tid; j < rsz; j += 1024)
        sh[j] = bh[(size_t)c * nbins + rlo + j];
    __syncthreads();
    const int end = (c + 1) * CHSZ;
    for (int i = c * CHSZ + tid; i < end; i += 1024) {
        int kv = key[i];
        unsigned v = (unsigned)(kv - rlo);
        if (v < (unsigned)rsz) {
            int pos = atomicAdd(&sh[v], 1);
            csr[pos] = payload[i];
        }
    }
}

// ---- segmented sum (pull) + optional fused BN/sigmoid finalize ----
__global__ __launch_bounds__(256) void seg_sum_fin(
    const float* __restrict__ table, const int* __restrict__ csr,
    const int* __restrict__ off, const float* __restrict__ x,
    const float* __restrict__ g, const float* __restrict__ bb,
    const float* __restrict__ mm, const float* __restrict__ vv,
    float* __restrict__ agg_out, float* __restrict__ fin_out, int nseg)
{
    int gid = blockIdx.x * blockDim.x + threadIdx.x;
    int seg = gid >> 5;
    if (seg >= nseg) return;
    int q = (gid & 31) * 4;
    int i0 = off[seg], i1 = off[seg + 1];
    float4 acc = make_float4(0.f, 0.f, 0.f, 0.f);
    int i = i0;
    for (; i + 1 < i1; i += 2) {
        int r0 = csr[i], r1 = csr[i + 1];
        float4 a0 = *(const float4*)(table + (size_t)r0 * FDIM + q);
        float4 a1 = *(const float4*)(table + (size_t)r1 * FDIM + q);
        acc = f4add(acc, f4add(a0, a1));
    }
    if (i < i1) {
        int r = csr[i];
        acc = f4add(acc, *(const float4*)(table + (size_t)r * FDIM + q));
    }
    if (agg_out)
        *(float4*)(agg_out + (size_t)seg * FDIM + q) = acc;
    if (fin_out) {
        float4 xv = *(const float4*)(x + (size_t)seg * FDIM + q);
        float4 gg = *(const float4*)(g + q);
        float4 bt = *(const float4*)(bb + q);
        float4 mn = *(const float4*)(mm + q);
        float4 vr = *(const float4*)(vv + q);
        float4 o;
        o.x = sigmoidf_((xv.x - mn.x) * (gg.x * rsqrtf(vr.x + BN_EPS)) + bt.x + acc.x);
        o.y = sigmoidf_((xv.y - mn.y) * (gg.y * rsqrtf(vr.y + BN_EPS)) + bt.y + acc.y);
        o.z = sigmoidf_((xv.z - mn.z) * (gg.z * rsqrtf(vr.z + BN_EPS)) + bt.z + acc.z);
        o.w = sigmoidf_((xv.w - mn.w) * (gg.w * rsqrtf(vr.w + BN_EPS)) + bt.w + acc.w);
        *(float4*)(fin_out + (size_t)seg * FDIM + q) = o;
    }
}

extern "C" void kernel_launch(void* const* d_in, const int* in_sizes, int n_in,
                              void* d_out, int out_size, void* d_ws, size_t ws_size,
                              hipStream_t stream)
{
    const float* x0       = (const float*)d_in[0];
    const float* x1       = (const float*)d_in[1];
    const int*   node_idx = (const int*)d_in[2];
    const int*   edge_idx = (const int*)d_in[3];
    const float* W_nh     = (const float*)d_in[4];
    const float* b_nh     = (const float*)d_in[5];
    const float* W_en     = (const float*)d_in[6];
    const float* b_en     = (const float*)d_in[7];
    const float* bn0g = (const float*)d_in[8];
    const float* bn0b = (const float*)d_in[9];
    const float* bn0m = (const float*)d_in[10];
    const float* bn0v = (const float*)d_in[11];
    const float* bn1g = (const float*)d_in[12];
    const float* bn1b = (const float*)d_in[13];
    const float* bn1m = (const float*)d_in[14];
    const float* bn1v = (const float*)d_in[15];

    float* ws = (float*)d_ws;
    float* A    = ws;                           // node_messages [100000,128]
    float* B    = A + (size_t)NNODES * FDIM;    // node_msg_agg  [20000,128]
    float* D    = B + (size_t)NEDGES * FDIM;    // he_messages   [20000,128]
    float* WTnh = D + (size_t)NEDGES * FDIM;    // [128,128]
    float* WTen = WTnh + FDIM * FDIM;           // [256,128]
    int* ip    = (int*)(WTen + 2 * FDIM * FDIM);
    int* cnt_e = ip;                    // 20000
    int* cnt_n = cnt_e + NEDGES;        // 100000
    int* off_e = cnt_n + NNODES;        // 20001 (pad 20004)
    int* off_n = off_e + 20004;         // 100001 (pad 100004)
    int* csr_e = off_n + 100004;        // 2M: node row ids grouped by edge
    int* csr_n = csr_e + NNZ_;          // 2M: edge row ids grouped by node
    // per-chunk histograms alias A (dead before gemm1 writes A)
    int* bh_e = (int*)A;                // [NCHUNK][NEDGES]
    int* bh_n = bh_e + (size_t)NCHUNK * NEDGES;   // [NCHUNK][NNODES]

    const int nr_e = (NEDGES + RANGE - 1) / RANGE;   // 2
    const int nr_n = (NNODES + RANGE - 1) / RANGE;   // 7

    // --- CSR build (no global atomics) ---
    hist_range<<<dim3(NCHUNK, nr_e), 1024, 0, stream>>>(edge_idx, bh_e, NEDGES);
    hist_range<<<dim3(NCHUNK, nr_n), 1024, 0, stream>>>(node_idx, bh_n, NNODES);
    colsum<<<(NEDGES + 255) / 256, 256, 0, stream>>>(bh_e, cnt_e, NEDGES);
    colsum<<<(NNODES + 255) / 256, 256, 0, stream>>>(bh_n, cnt_n, NNODES);
    excl_scan<<<1, 1024, 0, stream>>>(cnt_e, off_e, NEDGES);
    excl_scan<<<1, 1024, 0, stream>>>(cnt_n, off_n, NNODES);
    rebase<<<(NEDGES + 255) / 256, 256, 0, stream>>>(bh_e, off_e, NEDGES);
    rebase<<<(NNODES + 255) / 256, 256, 0, stream>>>(bh_n, off_n, NNODES);
    fill_range<<<dim3(NCHUNK, nr_e), 1024, 0, stream>>>(edge_idx, node_idx, bh_e, csr_e, NEDGES);
    fill_range<<<dim3(NCHUNK, nr_n), 1024, 0, stream>>>(node_idx, edge_idx, bh_n, csr_n, NNODES);

    // weight transposes
    transpose_w<<<(FDIM * FDIM + 255) / 256, 256, 0, stream>>>(W_nh, WTnh, FDIM);
    transpose_w<<<(2 * FDIM * FDIM + 255) / 256, 256, 0, stream>>>(W_en, WTen, 2 * FDIM);

    float* out0 = (float*)d_out;
    float* out1 = out0 + (size_t)NNODES * FDIM;

    // node -> hyperedge: GEMM1 then pull-aggregate onto edges (+ fused x1_out)
    gemm_sig<128><<<NNODES / 32, 256, 0, stream>>>(x0, nullptr, WTnh, b_nh, A);
    seg_sum_fin<<<(NEDGES * 32 + 255) / 256, 256, 0, stream>>>(
        A, csr_e, off_e, x1, bn1g, bn1b, bn1m, bn1v, B, out1, NEDGES);

    // hyperedge -> node: GEMM2 then pull-aggregate onto nodes (+ fused x0_out)
    gemm_sig<256><<<NEDGES / 32, 256, 0, stream>>>(x1, B, WTen, b_en, D);
    seg_sum_fin<<<(NNODES * 32 + 255) / 256, 256, 0, stream>>>(
        D, csr_n, off_n, x0, bn0g, bn0b, bn0m, bn0v, nullptr, out0, NNODES);
}

// Round 4
// 681.670 us; speedup vs baseline: 10.1742x; 1.2406x over previous
//
#include <hip/hip_runtime.h>
#include <math.h>

#define NNODES 100000
#define NEDGES 20000
#define NNZ_   2000000
#define FDIM   128
#define BN_EPS 1e-5f

#define NCHUNK 32
#define CHSZ   (NNZ_ / NCHUNK)   // 62500
#define RANGE  16000             // bins per LDS pass (64000 B LDS)

__device__ __forceinline__ float sigmoidf_(float x) {
    return 1.0f / (1.0f + __expf(-x));
}
__device__ __forceinline__ float4 f4add(float4 a, float4 b) {
    a.x += b.x; a.y += b.y; a.z += b.z; a.w += b.w; return a;
}

// ---- transpose W[128,K] (row-major) -> WT[K,128] (k-major) ----
__global__ __launch_bounds__(256) void transpose_w(const float* __restrict__ W,
                                                   float* __restrict__ WT, int K) {
    int idx = blockIdx.x * blockDim.x + threadIdx.x;
    if (idx >= K * FDIM) return;
    int k = idx >> 7;
    int c = idx & 127;
    WT[idx] = W[c * K + k];
}

// ---- out[M,128] = sigmoid(cat(A1,A2)[M,K] @ W[128,K]^T + b) ----
template<int K>
__global__ __launch_bounds__(256, 2) void gemm_sig(
    const float* __restrict__ A1, const float* __restrict__ A2,
    const float* __restrict__ WT, const float* __restrict__ bias,
    float* __restrict__ out)
{
    constexpr int BK = 64;
    constexpr int TM = 32;
    __shared__ float As[TM][BK + 4];
    __shared__ float Ws[BK][FDIM];
    const int tid  = threadIdx.x;
    const int row0 = blockIdx.x * TM;
    const int tcol = tid & 31;
    const int trow = tid >> 5;
    float acc[4][4] = {};

    for (int kk = 0; kk < K; kk += BK) {
        const float* Asrc = (kk < FDIM) ? A1 : A2;
        const int koff    = (kk < FDIM) ? kk : kk - FDIM;
        #pragma unroll
        for (int i = 0; i < 2; i++) {
            int l = tid + i * 256;
            int r = l >> 4, j = l & 15;
            float4 v = *(const float4*)(Asrc + (size_t)(row0 + r) * FDIM + koff + j * 4);
            *(float4*)&As[r][j * 4] = v;
        }
        #pragma unroll
        for (int i = 0; i < 8; i++) {
            int l = tid + i * 256;
            int k = l >> 5, j = l & 31;
            float4 v = *(const float4*)(WT + (size_t)(kk + k) * FDIM + j * 4);
            *(float4*)&Ws[k][j * 4] = v;
        }
        __syncthreads();
        #pragma unroll
        for (int k = 0; k < BK; k += 4) {
            float4 a[4];
            #pragma unroll
            for (int r = 0; r < 4; r++)
                a[r] = *(const float4*)&As[trow * 4 + r][k];
            #pragma unroll
            for (int kq = 0; kq < 4; kq++) {
                float4 w = *(const float4*)&Ws[k + kq][tcol * 4];
                #pragma unroll
                for (int r = 0; r < 4; r++) {
                    float av = (kq == 0) ? a[r].x : (kq == 1) ? a[r].y
                             : (kq == 2) ? a[r].z : a[r].w;
                    acc[r][0] += av * w.x;
                    acc[r][1] += av * w.y;
                    acc[r][2] += av * w.z;
                    acc[r][3] += av * w.w;
                }
            }
        }
        __syncthreads();
    }
    float4 bv = *(const float4*)(bias + tcol * 4);
    #pragma unroll
    for (int r = 0; r < 4; r++) {
        int row = row0 + trow * 4 + r;
        float4 o;
        o.x = sigmoidf_(acc[r][0] + bv.x);
        o.y = sigmoidf_(acc[r][1] + bv.y);
        o.z = sigmoidf_(acc[r][2] + bv.z);
        o.w = sigmoidf_(acc[r][3] + bv.w);
        *(float4*)(out + (size_t)row * FDIM + tcol * 4) = o;
    }
}

// ---- CSR build, atomic-free at device scope ----
__global__ __launch_bounds__(1024) void hist_range(
    const int* __restrict__ key, int* __restrict__ bh, int nbins)
{
    __shared__ int sh[RANGE];
    const int c   = blockIdx.x;
    const int rlo = blockIdx.y * RANGE;
    const int rsz = min(RANGE, nbins - rlo);
    const int tid = threadIdx.x;
    for (int j = tid; j < rsz; j += 1024) sh[j] = 0;
    __syncthreads();
    const int end = (c + 1) * CHSZ;
    for (int i = c * CHSZ + tid; i < end; i += 1024) {
        unsigned v = (unsigned)(key[i] - rlo);
        if (v < (unsigned)rsz) atomicAdd(&sh[v], 1);
    }
    __syncthreads();
    for (int j = tid; j < rsz; j += 1024)
        bh[(size_t)c * nbins + rlo + j] = sh[j];
}

// cnt[bin] = sum over chunks of bh[c][bin]
__global__ __launch_bounds__(256) void colsum(
    const int* __restrict__ bh, int* __restrict__ cnt, int nbins)
{
    int bin = blockIdx.x * blockDim.x + threadIdx.x;
    if (bin >= nbins) return;
    int s = 0;
    #pragma unroll 4
    for (int c = 0; c < NCHUNK; c++) s += bh[(size_t)c * nbins + bin];
    cnt[bin] = s;
}

// ---- hierarchical exclusive scan (3 passes, all parallel) ----
#define SCAN_TILE 1024

__global__ __launch_bounds__(256) void scan_blksum(
    const int* __restrict__ cnt, int* __restrict__ bsum, int n)
{
    int t = threadIdx.x;
    int base = blockIdx.x * SCAN_TILE;
    int s = 0;
    #pragma unroll
    for (int k = 0; k < 4; k++) {
        int i = base + t + k * 256;
        if (i < n) s += cnt[i];
    }
    #pragma unroll
    for (int d = 32; d > 0; d >>= 1) s += __shfl_down(s, d, 64);
    __shared__ int sh[4];
    if ((t & 63) == 0) sh[t >> 6] = s;
    __syncthreads();
    if (t == 0) bsum[blockIdx.x] = sh[0] + sh[1] + sh[2] + sh[3];
}

// single small block: exclusive scan of bsum[nb] in place (nb <= 256)
__global__ __launch_bounds__(256) void scan_bsums(int* __restrict__ bsum, int nb)
{
    __shared__ int sh[256];
    int t = threadIdx.x;
    int v = (t < nb) ? bsum[t] : 0;
    sh[t] = v;
    __syncthreads();
    for (int d = 1; d < 256; d <<= 1) {
        int u = (t >= d) ? sh[t - d] : 0;
        __syncthreads();
        sh[t] += u;
        __syncthreads();
    }
    if (t < nb) bsum[t] = sh[t] - v;
}

__global__ __launch_bounds__(256) void scan_final(
    const int* __restrict__ cnt, const int* __restrict__ bsum,
    int* __restrict__ off, int n)
{
    __shared__ int sh[256];
    int t = threadIdx.x;
    int base = blockIdx.x * SCAN_TILE + t * 4;
    int v[4];
    int s = 0;
    #pragma unroll
    for (int k = 0; k < 4; k++) {
        int i = base + k;
        v[k] = (i < n) ? cnt[i] : 0;
        s += v[k];
    }
    sh[t] = s;
    __syncthreads();
    for (int d = 1; d < 256; d <<= 1) {
        int u = (t >= d) ? sh[t - d] : 0;
        __syncthreads();
        sh[t] += u;
        __syncthreads();
    }
    int run = bsum[blockIdx.x] + sh[t] - s;
    #pragma unroll
    for (int k = 0; k < 4; k++) {
        int i = base + k;
        if (i < n) off[i] = run;
        run += v[k];
        if (i == n - 1) off[n] = run;
    }
}

// bh[c][bin] := off[bin] + prefix over chunks (per-(chunk,bin) start positions)
__global__ __launch_bounds__(256) void rebase(
    int* __restrict__ bh, const int* __restrict__ off, int nbins)
{
    int bin = blockIdx.x * blockDim.x + threadIdx.x;
    if (bin >= nbins) return;
    int run = off[bin];
    for (int c = 0; c < NCHUNK; c++) {
        size_t p = (size_t)c * nbins + bin;
        int old = bh[p];
        bh[p] = run;
        run += old;
    }
}

// fill: LDS cursors, LDS fetch-add rank, plain scattered store
__global__ __launch_bounds__(1024) void fill_range(
    const int* __restrict__ key, const int* __restrict__ payload,
    const int* __restrict__ bh, int* __restrict__ csr, int nbins)
{
    __shared__ int sh[RANGE];
    const int c   = blockIdx.x;
    const int rlo = blockIdx.y * RANGE;
    const int rsz = min(RANGE, nbins - rlo);
    const int tid = threadIdx.x;
    for (int j = tid; j < rsz; j += 1024)
        sh[j] = bh[(size_t)c * nbins + rlo + j];
    __syncthreads();
    const int end = (c + 1) * CHSZ;
    for (int i = c * CHSZ + tid; i < end; i += 1024) {
        int kv = key[i];
        unsigned v = (unsigned)(kv - rlo);
        if (v < (unsigned)rsz) {
            int pos = atomicAdd(&sh[v], 1);
            csr[pos] = payload[i];
        }
    }
}

// ---- segmented sum (pull) + optional fused BN/sigmoid finalize ----
__global__ __launch_bounds__(256) void seg_sum_fin(
    const float* __restrict__ table, const int* __restrict__ csr,
    const int* __restrict__ off, const float* __restrict__ x,
    const float* __restrict__ g, const float* __restrict__ bb,
    const float* __restrict__ mm, const float* __restrict__ vv,
    float* __restrict__ agg_out, float* __restrict__ fin_out, int nseg)
{
    int gid = blockIdx.x * blockDim.x + threadIdx.x;
    int seg = gid >> 5;
    if (seg >= nseg) return;
    int q = (gid & 31) * 4;
    int i0 = off[seg], i1 = off[seg + 1];
    float4 acc = make_float4(0.f, 0.f, 0.f, 0.f);
    int i = i0;
    for (; i + 1 < i1; i += 2) {
        int r0 = csr[i], r1 = csr[i + 1];
        float4 a0 = *(const float4*)(table + (size_t)r0 * FDIM + q);
        float4 a1 = *(const float4*)(table + (size_t)r1 * FDIM + q);
        acc = f4add(acc, f4add(a0, a1));
    }
    if (i < i1) {
        int r = csr[i];
        acc = f4add(acc, *(const float4*)(table + (size_t)r * FDIM + q));
    }
    if (agg_out)
        *(float4*)(agg_out + (size_t)seg * FDIM + q) = acc;
    if (fin_out) {
        float4 xv = *(const float4*)(x + (size_t)seg * FDIM + q);
        float4 gg = *(const float4*)(g + q);
        float4 bt = *(const float4*)(bb + q);
        float4 mn = *(const float4*)(mm + q);
        float4 vr = *(const float4*)(vv + q);
        float4 o;
        o.x = sigmoidf_((xv.x - mn.x) * (gg.x * rsqrtf(vr.x + BN_EPS)) + bt.x + acc.x);
        o.y = sigmoidf_((xv.y - mn.y) * (gg.y * rsqrtf(vr.y + BN_EPS)) + bt.y + acc.y);
        o.z = sigmoidf_((xv.z - mn.z) * (gg.z * rsqrtf(vr.z + BN_EPS)) + bt.z + acc.z);
        o.w = sigmoidf_((xv.w - mn.w) * (gg.w * rsqrtf(vr.w + BN_EPS)) + bt.w + acc.w);
        *(float4*)(fin_out + (size_t)seg * FDIM + q) = o;
    }
}

extern "C" void kernel_launch(void* const* d_in, const int* in_sizes, int n_in,
                              void* d_out, int out_size, void* d_ws, size_t ws_size,
                              hipStream_t stream)
{
    const float* x0       = (const float*)d_in[0];
    const float* x1       = (const float*)d_in[1];
    const int*   node_idx = (const int*)d_in[2];
    const int*   edge_idx = (const int*)d_in[3];
    const float* W_nh     = (const float*)d_in[4];
    const float* b_nh     = (const float*)d_in[5];
    const float* W_en     = (const float*)d_in[6];
    const float* b_en     = (const float*)d_in[7];
    const float* bn0g = (const float*)d_in[8];
    const float* bn0b = (const float*)d_in[9];
    const float* bn0m = (const float*)d_in[10];
    const float* bn0v = (const float*)d_in[11];
    const float* bn1g = (const float*)d_in[12];
    const float* bn1b = (const float*)d_in[13];
    const float* bn1m = (const float*)d_in[14];
    const float* bn1v = (const float*)d_in[15];

    float* ws = (float*)d_ws;
    float* A    = ws;                           // node_messages [100000,128]
    float* B    = A + (size_t)NNODES * FDIM;    // node_msg_agg  [20000,128]
    float* D    = B + (size_t)NEDGES * FDIM;    // he_messages   [20000,128]
    float* WTnh = D + (size_t)NEDGES * FDIM;    // [128,128]
    float* WTen = WTnh + FDIM * FDIM;           // [256,128]
    int* ip    = (int*)(WTen + 2 * FDIM * FDIM);
    int* cnt_e = ip;                    // 20000
    int* cnt_n = cnt_e + NEDGES;        // 100000
    int* off_e = cnt_n + NNODES;        // 20001 (pad 20004)
    int* off_n = off_e + 20004;         // 100001 (pad 100004)
    int* csr_e = off_n + 100004;        // 2M
    int* csr_n = csr_e + NNZ_;          // 2M
    int* bsum_e = csr_n + NNZ_;         // 20
    int* bsum_n = bsum_e + 32;          // 98
    // per-chunk histograms alias A (dead before gemm1 writes A)
    int* bh_e = (int*)A;                // [NCHUNK][NEDGES]
    int* bh_n = bh_e + (size_t)NCHUNK * NEDGES;   // [NCHUNK][NNODES]

    const int nr_e = (NEDGES + RANGE - 1) / RANGE;   // 2
    const int nr_n = (NNODES + RANGE - 1) / RANGE;   // 7
    const int nb_e = (NEDGES + SCAN_TILE - 1) / SCAN_TILE;   // 20
    const int nb_n = (NNODES + SCAN_TILE - 1) / SCAN_TILE;   // 98

    // --- CSR build (no global atomics) ---
    hist_range<<<dim3(NCHUNK, nr_e), 1024, 0, stream>>>(edge_idx, bh_e, NEDGES);
    hist_range<<<dim3(NCHUNK, nr_n), 1024, 0, stream>>>(node_idx, bh_n, NNODES);
    colsum<<<(NEDGES + 255) / 256, 256, 0, stream>>>(bh_e, cnt_e, NEDGES);
    colsum<<<(NNODES + 255) / 256, 256, 0, stream>>>(bh_n, cnt_n, NNODES);
    scan_blksum<<<nb_e, 256, 0, stream>>>(cnt_e, bsum_e, NEDGES);
    scan_bsums<<<1, 256, 0, stream>>>(bsum_e, nb_e);
    scan_final<<<nb_e, 256, 0, stream>>>(cnt_e, bsum_e, off_e, NEDGES);
    scan_blksum<<<nb_n, 256, 0, stream>>>(cnt_n, bsum_n, NNODES);
    scan_bsums<<<1, 256, 0, stream>>>(bsum_n, nb_n);
    scan_final<<<nb_n, 256, 0, stream>>>(cnt_n, bsum_n, off_n, NNODES);
    rebase<<<(NEDGES + 255) / 256, 256, 0, stream>>>(bh_e, off_e, NEDGES);
    rebase<<<(NNODES + 255) / 256, 256, 0, stream>>>(bh_n, off_n, NNODES);
    fill_range<<<dim3(NCHUNK, nr_e), 1024, 0, stream>>>(edge_idx, node_idx, bh_e, csr_e, NEDGES);
    fill_range<<<dim3(NCHUNK, nr_n), 1024, 0, stream>>>(node_idx, edge_idx, bh_n, csr_n, NNODES);

    // weight transposes
    transpose_w<<<(FDIM * FDIM + 255) / 256, 256, 0, stream>>>(W_nh, WTnh, FDIM);
    transpose_w<<<(2 * FDIM * FDIM + 255) / 256, 256, 0, stream>>>(W_en, WTen, 2 * FDIM);

    float* out0 = (float*)d_out;
    float* out1 = out0 + (size_t)NNODES * FDIM;

    // node -> hyperedge: GEMM1 then pull-aggregate onto edges (+ fused x1_out)
    gemm_sig<128><<<NNODES / 32, 256, 0, stream>>>(x0, nullptr, WTnh, b_nh, A);
    seg_sum_fin<<<(NEDGES * 32 + 255) / 256, 256, 0, stream>>>(
        A, csr_e, off_e, x1, bn1g, bn1b, bn1m, bn1v, B, out1, NEDGES);

    // hyperedge -> node: GEMM2 then pull-aggregate onto nodes (+ fused x0_out)
    gemm_sig<256><<<NEDGES / 32, 256, 0, stream>>>(x1, B, WTen, b_en, D);
    seg_sum_fin<<<(NNODES * 32 + 255) / 256, 256, 0, stream>>>(
        D, csr_n, off_n, x0, bn0g, bn0b, bn0m, bn0v, nullptr, out0, NNODES);
}

// Round 5
// 492.610 us; speedup vs baseline: 14.0790x; 1.3838x over previous
//
#include <hip/hip_runtime.h>
#include <hip/hip_bf16.h>
#include <math.h>

#define NNODES 100000
#define NEDGES 20000
#define NNZ_   2000000
#define FDIM   128
#define BN_EPS 1e-5f

#define NCHUNK 32
#define CHSZ   (NNZ_ / NCHUNK)   // 62500
#define RANGE  16000             // bins per LDS pass (64000 B static LDS)
#define NR_E   ((NEDGES + RANGE - 1) / RANGE)   // 2
#define NR_N   ((NNODES + RANGE - 1) / RANGE)   // 7
#define SCAN_TILE 1024
#define NB_E   ((NEDGES + SCAN_TILE - 1) / SCAN_TILE)   // 20
#define NB_N   ((NNODES + SCAN_TILE - 1) / SCAN_TILE)   // 98

__device__ __forceinline__ float sigmoidf_(float x) {
    return 1.0f / (1.0f + __expf(-x));
}
__device__ __forceinline__ float bf2f(unsigned short u) {
    return __uint_as_float(((unsigned)u) << 16);
}
__device__ __forceinline__ unsigned short f2bf(float f) {
    __hip_bfloat16 h = __float2bfloat16(f);   // RNE
    return *reinterpret_cast<unsigned short*>(&h);
}

// ---- both weight transposes in one launch ----
// W_nh[128,128] -> WTnh[128,128] k-major ; W_en[128,256] -> WTen[256,128] k-major
__global__ __launch_bounds__(256) void transpose2(
    const float* __restrict__ W_nh, const float* __restrict__ W_en,
    float* __restrict__ WTnh, float* __restrict__ WTen)
{
    int idx = blockIdx.x * blockDim.x + threadIdx.x;
    if (idx < FDIM * FDIM) {
        int k = idx >> 7, c = idx & 127;
        WTnh[idx] = W_nh[c * FDIM + k];
    } else {
        int j = idx - FDIM * FDIM;
        if (j >= 2 * FDIM * FDIM) return;
        int k = j >> 7, c = j & 127;
        WTen[j] = W_en[c * 2 * FDIM + k];
    }
}

// ---- out[M,128] = sigmoid(cat(A1,A2)[M,K] @ W[128,K]^T + b), bf16 output ----
template<int K>
__global__ __launch_bounds__(256, 2) void gemm_sig_bf16(
    const float* __restrict__ A1, const float* __restrict__ A2,
    const float* __restrict__ WT, const float* __restrict__ bias,
    unsigned short* __restrict__ out)
{
    constexpr int BK = 64;
    constexpr int TM = 32;
    __shared__ float As[TM][BK + 4];
    __shared__ float Ws[BK][FDIM];
    const int tid  = threadIdx.x;
    const int row0 = blockIdx.x * TM;
    const int tcol = tid & 31;
    const int trow = tid >> 5;
    float acc[4][4] = {};

    for (int kk = 0; kk < K; kk += BK) {
        const float* Asrc = (kk < FDIM) ? A1 : A2;
        const int koff    = (kk < FDIM) ? kk : kk - FDIM;
        #pragma unroll
        for (int i = 0; i < 2; i++) {
            int l = tid + i * 256;
            int r = l >> 4, j = l & 15;
            float4 v = *(const float4*)(Asrc + (size_t)(row0 + r) * FDIM + koff + j * 4);
            *(float4*)&As[r][j * 4] = v;
        }
        #pragma unroll
        for (int i = 0; i < 8; i++) {
            int l = tid + i * 256;
            int k = l >> 5, j = l & 31;
            float4 v = *(const float4*)(WT + (size_t)(kk + k) * FDIM + j * 4);
            *(float4*)&Ws[k][j * 4] = v;
        }
        __syncthreads();
        #pragma unroll
        for (int k = 0; k < BK; k += 4) {
            float4 a[4];
            #pragma unroll
            for (int r = 0; r < 4; r++)
                a[r] = *(const float4*)&As[trow * 4 + r][k];
            #pragma unroll
            for (int kq = 0; kq < 4; kq++) {
                float4 w = *(const float4*)&Ws[k + kq][tcol * 4];
                #pragma unroll
                for (int r = 0; r < 4; r++) {
                    float av = (kq == 0) ? a[r].x : (kq == 1) ? a[r].y
                             : (kq == 2) ? a[r].z : a[r].w;
                    acc[r][0] += av * w.x;
                    acc[r][1] += av * w.y;
                    acc[r][2] += av * w.z;
                    acc[r][3] += av * w.w;
                }
            }
        }
        __syncthreads();
    }
    float4 bv = *(const float4*)(bias + tcol * 4);
    #pragma unroll
    for (int r = 0; r < 4; r++) {
        int row = row0 + trow * 4 + r;
        ushort4 o;
        o.x = f2bf(sigmoidf_(acc[r][0] + bv.x));
        o.y = f2bf(sigmoidf_(acc[r][1] + bv.y));
        o.z = f2bf(sigmoidf_(acc[r][2] + bv.z));
        o.w = f2bf(sigmoidf_(acc[r][3] + bv.w));
        *(ushort4*)(out + (size_t)row * FDIM + tcol * 4) = o;
    }
}

// ---- CSR build (edge+node fused per launch, no global atomics) ----
__global__ __launch_bounds__(1024) void hist2(
    const int* __restrict__ edge_key, const int* __restrict__ node_key,
    int* __restrict__ bh_e, int* __restrict__ bh_n)
{
    __shared__ int sh[RANGE];
    const int c  = blockIdx.x;
    const int by = blockIdx.y;
    const int* key; int* bh; int nbins, rlo;
    if (by < NR_E) { key = edge_key; bh = bh_e; nbins = NEDGES; rlo = by * RANGE; }
    else           { key = node_key; bh = bh_n; nbins = NNODES; rlo = (by - NR_E) * RANGE; }
    const int rsz = min(RANGE, nbins - rlo);
    const int tid = threadIdx.x;
    for (int j = tid; j < rsz; j += 1024) sh[j] = 0;
    __syncthreads();
    const int end = (c + 1) * CHSZ;
    for (int i = c * CHSZ + tid; i < end; i += 1024) {
        unsigned v = (unsigned)(key[i] - rlo);
        if (v < (unsigned)rsz) atomicAdd(&sh[v], 1);
    }
    __syncthreads();
    for (int j = tid; j < rsz; j += 1024)
        bh[(size_t)c * nbins + rlo + j] = sh[j];
}

__global__ __launch_bounds__(256) void colsum2(
    const int* __restrict__ bh_e, const int* __restrict__ bh_n,
    int* __restrict__ cnt_e, int* __restrict__ cnt_n)
{
    int g = blockIdx.x * blockDim.x + threadIdx.x;
    const int* bh; int* cnt; int nbins, bin;
    if (g < NEDGES) { bh = bh_e; cnt = cnt_e; nbins = NEDGES; bin = g; }
    else            { bh = bh_n; cnt = cnt_n; nbins = NNODES; bin = g - NEDGES;
                      if (bin >= NNODES) return; }
    int s = 0;
    #pragma unroll 4
    for (int c = 0; c < NCHUNK; c++) s += bh[(size_t)c * nbins + bin];
    cnt[bin] = s;
}

__global__ __launch_bounds__(256) void scan_blksum2(
    const int* __restrict__ cnt_e, const int* __restrict__ cnt_n,
    int* __restrict__ bsum_e, int* __restrict__ bsum_n)
{
    int b = blockIdx.x;
    const int* cnt; int* bsum; int n, lb;
    if (b < NB_E) { cnt = cnt_e; bsum = bsum_e; n = NEDGES; lb = b; }
    else          { cnt = cnt_n; bsum = bsum_n; n = NNODES; lb = b - NB_E; }
    int t = threadIdx.x;
    int base = lb * SCAN_TILE;
    int s = 0;
    #pragma unroll
    for (int k = 0; k < 4; k++) {
        int i = base + t + k * 256;
        if (i < n) s += cnt[i];
    }
    #pragma unroll
    for (int d = 32; d > 0; d >>= 1) s += __shfl_down(s, d, 64);
    __shared__ int sh[4];
    if ((t & 63) == 0) sh[t >> 6] = s;
    __syncthreads();
    if (t == 0) bsum[lb] = sh[0] + sh[1] + sh[2] + sh[3];
}

__global__ __launch_bounds__(256) void scan_bsums2(int* __restrict__ bsum_e,
                                                   int* __restrict__ bsum_n)
{
    __shared__ int sh[256];
    int* bsum = (blockIdx.x == 0) ? bsum_e : bsum_n;
    int nb    = (blockIdx.x == 0) ? NB_E : NB_N;
    int t = threadIdx.x;
    int v = (t < nb) ? bsum[t] : 0;
    sh[t] = v;
    __syncthreads();
    for (int d = 1; d < 256; d <<= 1) {
        int u = (t >= d) ? sh[t - d] : 0;
        __syncthreads();
        sh[t] += u;
        __syncthreads();
    }
    if (t < nb) bsum[t] = sh[t] - v;
}

__global__ __launch_bounds__(256) void scan_final2(
    const int* __restrict__ cnt_e, const int* __restrict__ cnt_n,
    const int* __restrict__ bsum_e, const int* __restrict__ bsum_n,
    int* __restrict__ off_e, int* __restrict__ off_n)
{
    int b = blockIdx.x;
    const int* cnt; const int* bsum; int* off; int n, lb;
    if (b < NB_E) { cnt = cnt_e; bsum = bsum_e; off = off_e; n = NEDGES; lb = b; }
    else          { cnt = cnt_n; bsum = bsum_n; off = off_n; n = NNODES; lb = b - NB_E; }
    __shared__ int sh[256];
    int t = threadIdx.x;
    int base = lb * SCAN_TILE + t * 4;
    int v[4];
    int s = 0;
    #pragma unroll
    for (int k = 0; k < 4; k++) {
        int i = base + k;
        v[k] = (i < n) ? cnt[i] : 0;
        s += v[k];
    }
    sh[t] = s;
    __syncthreads();
    for (int d = 1; d < 256; d <<= 1) {
        int u = (t >= d) ? sh[t - d] : 0;
        __syncthreads();
        sh[t] += u;
        __syncthreads();
    }
    int run = bsum[lb] + sh[t] - s;
    #pragma unroll
    for (int k = 0; k < 4; k++) {
        int i = base + k;
        if (i < n) off[i] = run;
        run += v[k];
        if (i == n - 1) off[n] = run;
    }
}

__global__ __launch_bounds__(256) void rebase2(
    int* __restrict__ bh_e, int* __restrict__ bh_n,
    const int* __restrict__ off_e, const int* __restrict__ off_n)
{
    int g = blockIdx.x * blockDim.x + threadIdx.x;
    int* bh; const int* off; int nbins, bin;
    if (g < NEDGES) { bh = bh_e; off = off_e; nbins = NEDGES; bin = g; }
    else            { bh = bh_n; off = off_n; nbins = NNODES; bin = g - NEDGES;
                      if (bin >= NNODES) return; }
    int run = off[bin];
    for (int c = 0; c < NCHUNK; c++) {
        size_t p = (size_t)c * nbins + bin;
        int old = bh[p];
        bh[p] = run;
        run += old;
    }
}

__global__ __launch_bounds__(1024) void fill2(
    const int* __restrict__ edge_key, const int* __restrict__ node_key,
    const int* __restrict__ bh_e, const int* __restrict__ bh_n,
    int* __restrict__ csr_e, int* __restrict__ csr_n)
{
    __shared__ int sh[RANGE];
    const int c  = blockIdx.x;
    const int by = blockIdx.y;
    const int* key; const int* payload; const int* bh; int* csr; int nbins, rlo;
    if (by < NR_E) { key = edge_key; payload = node_key; bh = bh_e; csr = csr_e;
                     nbins = NEDGES; rlo = by * RANGE; }
    else           { key = node_key; payload = edge_key; bh = bh_n; csr = csr_n;
                     nbins = NNODES; rlo = (by - NR_E) * RANGE; }
    const int rsz = min(RANGE, nbins - rlo);
    const int tid = threadIdx.x;
    for (int j = tid; j < rsz; j += 1024)
        sh[j] = bh[(size_t)c * nbins + rlo + j];
    __syncthreads();
    const int end = (c + 1) * CHSZ;
    for (int i = c * CHSZ + tid; i < end; i += 1024) {
        int kv = key[i];
        unsigned v = (unsigned)(kv - rlo);
        if (v < (unsigned)rsz) {
            int pos = atomicAdd(&sh[v], 1);
            csr[pos] = payload[i];
        }
    }
}

// ---- segmented sum over bf16 table + optional fused BN/sigmoid finalize ----
// 32 lanes per segment; lane handles 4 features (8 B bf16 gather per lane).
__global__ __launch_bounds__(256) void seg_sum_fin_bf16(
    const unsigned short* __restrict__ table, const int* __restrict__ csr,
    const int* __restrict__ off, const float* __restrict__ x,
    const float* __restrict__ g, const float* __restrict__ bb,
    const float* __restrict__ mm, const float* __restrict__ vv,
    float* __restrict__ agg_out, float* __restrict__ fin_out, int nseg)
{
    int gid = blockIdx.x * blockDim.x + threadIdx.x;
    int seg = gid >> 5;
    if (seg >= nseg) return;
    int q = (gid & 31) * 4;
    int i0 = off[seg], i1 = off[seg + 1];
    float4 acc = make_float4(0.f, 0.f, 0.f, 0.f);
    int i = i0;
    for (; i + 3 < i1; i += 4) {
        int r0 = csr[i], r1 = csr[i + 1], r2 = csr[i + 2], r3 = csr[i + 3];
        ushort4 a0 = *(const ushort4*)(table + (size_t)r0 * FDIM + q);
        ushort4 a1 = *(const ushort4*)(table + (size_t)r1 * FDIM + q);
        ushort4 a2 = *(const ushort4*)(table + (size_t)r2 * FDIM + q);
        ushort4 a3 = *(const ushort4*)(table + (size_t)r3 * FDIM + q);
        acc.x += (bf2f(a0.x) + bf2f(a1.x)) + (bf2f(a2.x) + bf2f(a3.x));
        acc.y += (bf2f(a0.y) + bf2f(a1.y)) + (bf2f(a2.y) + bf2f(a3.y));
        acc.z += (bf2f(a0.z) + bf2f(a1.z)) + (bf2f(a2.z) + bf2f(a3.z));
        acc.w += (bf2f(a0.w) + bf2f(a1.w)) + (bf2f(a2.w) + bf2f(a3.w));
    }
    for (; i < i1; i++) {
        int r = csr[i];
        ushort4 a = *(const ushort4*)(table + (size_t)r * FDIM + q);
        acc.x += bf2f(a.x); acc.y += bf2f(a.y);
        acc.z += bf2f(a.z); acc.w += bf2f(a.w);
    }
    if (agg_out)
        *(float4*)(agg_out + (size_t)seg * FDIM + q) = acc;
    if (fin_out) {
        float4 xv = *(const float4*)(x + (size_t)seg * FDIM + q);
        float4 gg = *(const float4*)(g + q);
        float4 bt = *(const float4*)(bb + q);
        float4 mn = *(const float4*)(mm + q);
        float4 vr = *(const float4*)(vv + q);
        float4 o;
        o.x = sigmoidf_((xv.x - mn.x) * (gg.x * rsqrtf(vr.x + BN_EPS)) + bt.x + acc.x);
        o.y = sigmoidf_((xv.y - mn.y) * (gg.y * rsqrtf(vr.y + BN_EPS)) + bt.y + acc.y);
        o.z = sigmoidf_((xv.z - mn.z) * (gg.z * rsqrtf(vr.z + BN_EPS)) + bt.z + acc.z);
        o.w = sigmoidf_((xv.w - mn.w) * (gg.w * rsqrtf(vr.w + BN_EPS)) + bt.w + acc.w);
        *(float4*)(fin_out + (size_t)seg * FDIM + q) = o;
    }
}

extern "C" void kernel_launch(void* const* d_in, const int* in_sizes, int n_in,
                              void* d_out, int out_size, void* d_ws, size_t ws_size,
                              hipStream_t stream)
{
    const float* x0       = (const float*)d_in[0];
    const float* x1       = (const float*)d_in[1];
    const int*   node_idx = (const int*)d_in[2];
    const int*   edge_idx = (const int*)d_in[3];
    const float* W_nh     = (const float*)d_in[4];
    const float* b_nh     = (const float*)d_in[5];
    const float* W_en     = (const float*)d_in[6];
    const float* b_en     = (const float*)d_in[7];
    const float* bn0g = (const float*)d_in[8];
    const float* bn0b = (const float*)d_in[9];
    const float* bn0m = (const float*)d_in[10];
    const float* bn0v = (const float*)d_in[11];
    const float* bn1g = (const float*)d_in[12];
    const float* bn1b = (const float*)d_in[13];
    const float* bn1m = (const float*)d_in[14];
    const float* bn1v = (const float*)d_in[15];

    float* ws = (float*)d_ws;
    float* B    = ws;                           // node_msg_agg fp32 [20000,128]
    float* WTnh = B + (size_t)NEDGES * FDIM;    // [128,128]
    float* WTen = WTnh + FDIM * FDIM;           // [256,128]
    unsigned short* A_bf = (unsigned short*)(WTen + 2 * FDIM * FDIM);  // [100000,128] bf16
    unsigned short* D_bf = A_bf + (size_t)NNODES * FDIM;               // [20000,128] bf16
    int* ip    = (int*)(D_bf + (size_t)NEDGES * FDIM);
    int* cnt_e = ip;                    // 20000
    int* cnt_n = cnt_e + NEDGES;        // 100000
    int* off_e = cnt_n + NNODES;        // 20001 (pad 20004)
    int* off_n = off_e + 20004;         // 100001 (pad 100004)
    int* csr_e = off_n + 100004;        // 2M
    int* csr_n = csr_e + NNZ_;          // 2M
    int* bsum_e = csr_n + NNZ_;         // 20 (pad 32)
    int* bsum_n = bsum_e + 32;          // 98 (pad 128)
    int* bh_e   = bsum_n + 128;         // [NCHUNK][NEDGES]
    int* bh_n   = bh_e + (size_t)NCHUNK * NEDGES;   // [NCHUNK][NNODES]

    // --- CSR build (7 launches, edge+node fused) ---
    hist2<<<dim3(NCHUNK, NR_E + NR_N), 1024, 0, stream>>>(edge_idx, node_idx, bh_e, bh_n);
    colsum2<<<(NEDGES + NNODES + 255) / 256, 256, 0, stream>>>(bh_e, bh_n, cnt_e, cnt_n);
    scan_blksum2<<<NB_E + NB_N, 256, 0, stream>>>(cnt_e, cnt_n, bsum_e, bsum_n);
    scan_bsums2<<<2, 256, 0, stream>>>(bsum_e, bsum_n);
    scan_final2<<<NB_E + NB_N, 256, 0, stream>>>(cnt_e, cnt_n, bsum_e, bsum_n, off_e, off_n);
    rebase2<<<(NEDGES + NNODES + 255) / 256, 256, 0, stream>>>(bh_e, bh_n, off_e, off_n);
    fill2<<<dim3(NCHUNK, NR_E + NR_N), 1024, 0, stream>>>(edge_idx, node_idx,
                                                          bh_e, bh_n, csr_e, csr_n);

    transpose2<<<(3 * FDIM * FDIM + 255) / 256, 256, 0, stream>>>(W_nh, W_en, WTnh, WTen);

    float* out0 = (float*)d_out;
    float* out1 = out0 + (size_t)NNODES * FDIM;

    // node -> hyperedge: GEMM1 (bf16 out) then pull-aggregate (+ fused x1_out)
    gemm_sig_bf16<128><<<NNODES / 32, 256, 0, stream>>>(x0, nullptr, WTnh, b_nh, A_bf);
    seg_sum_fin_bf16<<<(NEDGES * 32 + 255) / 256, 256, 0, stream>>>(
        A_bf, csr_e, off_e, x1, bn1g, bn1b, bn1m, bn1v, B, out1, NEDGES);

    // hyperedge -> node: GEMM2 (bf16 out) then pull-aggregate (+ fused x0_out)
    gemm_sig_bf16<256><<<NEDGES / 32, 256, 0, stream>>>(x1, B, WTen, b_en, D_bf);
    seg_sum_fin_bf16<<<(NNODES * 32 + 255) / 256, 256, 0, stream>>>(
        D_bf, csr_n, off_n, x0, bn0g, bn0b, bn0m, bn0v, nullptr, out0, NNODES);
}

// Round 6
// 423.501 us; speedup vs baseline: 16.3764x; 1.1632x over previous
//
#include <hip/hip_runtime.h>
#include <hip/hip_bf16.h>
#include <math.h>

#define NNODES 100000
#define NEDGES 20000
#define NNZ_   2000000
#define FDIM   128
#define BN_EPS 1e-5f

// ---- bucket-sort geometry ----
#define NBUCK 256
#define CAP   9216        // per-bucket slot capacity (mean ~7850, sigma ~89 -> +15 sigma)
#define BPB_E 79          // bins/bucket, edge dir  (254 buckets cover 20000)
#define BPB_N 391         // bins/bucket, node dir  (256 buckets cover 100000)
#define SH_E  17          // edge entry = (e<<17)|n
#define SH_N  15          // node entry = (n<<15)|e

__device__ __forceinline__ float sigmoidf_(float x) {
    return 1.0f / (1.0f + __expf(-x));
}
__device__ __forceinline__ float bf2f(unsigned short u) {
    return __uint_as_float(((unsigned)u) << 16);
}
__device__ __forceinline__ unsigned short f2bf(float f) {
    __hip_bfloat16 h = __float2bfloat16(f);   // RNE
    return *reinterpret_cast<unsigned short*>(&h);
}

// ---- both weight transposes in one launch ----
__global__ __launch_bounds__(256) void transpose2(
    const float* __restrict__ W_nh, const float* __restrict__ W_en,
    float* __restrict__ WTnh, float* __restrict__ WTen)
{
    int idx = blockIdx.x * blockDim.x + threadIdx.x;
    if (idx < FDIM * FDIM) {
        int k = idx >> 7, c = idx & 127;
        WTnh[idx] = W_nh[c * FDIM + k];
    } else {
        int j = idx - FDIM * FDIM;
        if (j >= 2 * FDIM * FDIM) return;
        int k = j >> 7, c = j & 127;
        WTen[j] = W_en[c * 2 * FDIM + k];
    }
}

// ---- out[M,128] = sigmoid(cat(A1,A2)[M,K] @ W[128,K]^T + b), bf16 output ----
template<int K>
__global__ __launch_bounds__(256, 2) void gemm_sig_bf16(
    const float* __restrict__ A1, const float* __restrict__ A2,
    const float* __restrict__ WT, const float* __restrict__ bias,
    unsigned short* __restrict__ out)
{
    constexpr int BK = 64;
    constexpr int TM = 32;
    __shared__ float As[TM][BK + 4];
    __shared__ float Ws[BK][FDIM];
    const int tid  = threadIdx.x;
    const int row0 = blockIdx.x * TM;
    const int tcol = tid & 31;
    const int trow = tid >> 5;
    float acc[4][4] = {};

    for (int kk = 0; kk < K; kk += BK) {
        const float* Asrc = (kk < FDIM) ? A1 : A2;
        const int koff    = (kk < FDIM) ? kk : kk - FDIM;
        #pragma unroll
        for (int i = 0; i < 2; i++) {
            int l = tid + i * 256;
            int r = l >> 4, j = l & 15;
            float4 v = *(const float4*)(Asrc + (size_t)(row0 + r) * FDIM + koff + j * 4);
            *(float4*)&As[r][j * 4] = v;
        }
        #pragma unroll
        for (int i = 0; i < 8; i++) {
            int l = tid + i * 256;
            int k = l >> 5, j = l & 31;
            float4 v = *(const float4*)(WT + (size_t)(kk + k) * FDIM + j * 4);
            *(float4*)&Ws[k][j * 4] = v;
        }
        __syncthreads();
        #pragma unroll
        for (int k = 0; k < BK; k += 4) {
            float4 a[4];
            #pragma unroll
            for (int r = 0; r < 4; r++)
                a[r] = *(const float4*)&As[trow * 4 + r][k];
            #pragma unroll
            for (int kq = 0; kq < 4; kq++) {
                float4 w = *(const float4*)&Ws[k + kq][tcol * 4];
                #pragma unroll
                for (int r = 0; r < 4; r++) {
                    float av = (kq == 0) ? a[r].x : (kq == 1) ? a[r].y
                             : (kq == 2) ? a[r].z : a[r].w;
                    acc[r][0] += av * w.x;
                    acc[r][1] += av * w.y;
                    acc[r][2] += av * w.z;
                    acc[r][3] += av * w.w;
                }
            }
        }
        __syncthreads();
    }
    float4 bv = *(const float4*)(bias + tcol * 4);
    #pragma unroll
    for (int r = 0; r < 4; r++) {
        int row = row0 + trow * 4 + r;
        ushort4 o;
        o.x = f2bf(sigmoidf_(acc[r][0] + bv.x));
        o.y = f2bf(sigmoidf_(acc[r][1] + bv.y));
        o.z = f2bf(sigmoidf_(acc[r][2] + bv.z));
        o.w = f2bf(sigmoidf_(acc[r][3] + bv.w));
        *(ushort4*)(out + (size_t)row * FDIM + tcol * 4) = o;
    }
}

// ---- Pass A: coarse bucket partition (both directions in one pass) ----
// Per-block LDS bucket histogram -> one global fetch-add per (block,bucket)
// -> block-contiguous runs inside each padded bucket region.
__global__ __launch_bounds__(1024) void bucket_scatter(
    const int* __restrict__ ni, const int* __restrict__ ei,
    unsigned* __restrict__ buck_e, unsigned* __restrict__ buck_n,
    int* __restrict__ gcur_e, int* __restrict__ gcur_n)
{
    __shared__ int lh_e[NBUCK], lh_n[NBUCK], lb_e[NBUCK], lb_n[NBUCK];
    const int t = threadIdx.x;
    if (t < NBUCK) { lh_e[t] = 0; lh_n[t] = 0; }
    __syncthreads();
    unsigned ent_e[4], ent_n[4];
    int be[4], bn[4], re[4], rn[4];
    const int base = blockIdx.x * 4096;
    #pragma unroll
    for (int j = 0; j < 4; j++) {
        int i = base + j * 1024 + t;
        if (i < NNZ_) {
            unsigned n = (unsigned)ni[i], e = (unsigned)ei[i];
            ent_e[j] = (e << SH_E) | n;  be[j] = (int)(e / BPB_E);
            ent_n[j] = (n << SH_N) | e;  bn[j] = (int)(n / BPB_N);
            re[j] = atomicAdd(&lh_e[be[j]], 1);
            rn[j] = atomicAdd(&lh_n[bn[j]], 1);
        } else { be[j] = -1; }
    }
    __syncthreads();
    if (t < NBUCK) {
        lb_e[t] = t * CAP + atomicAdd(&gcur_e[t], lh_e[t]);
        lb_n[t] = t * CAP + atomicAdd(&gcur_n[t], lh_n[t]);
    }
    __syncthreads();
    #pragma unroll
    for (int j = 0; j < 4; j++) {
        if (be[j] >= 0) {
            buck_e[(size_t)lb_e[be[j]] + re[j]] = ent_e[j];
            buck_n[(size_t)lb_n[bn[j]] + rn[j]] = ent_n[j];
        }
    }
}

// ---- tiny: exclusive scan of bucket counts -> compact bases ----
__global__ __launch_bounds__(256) void bucket_bases(
    const int* __restrict__ gcur_e, const int* __restrict__ gcur_n,
    int* __restrict__ base_e, int* __restrict__ base_n)
{
    __shared__ int sh[NBUCK];
    int t = threadIdx.x;
    int v = gcur_e[t]; sh[t] = v; __syncthreads();
    for (int d = 1; d < NBUCK; d <<= 1) {
        int u = (t >= d) ? sh[t - d] : 0; __syncthreads();
        sh[t] += u; __syncthreads();
    }
    base_e[t] = sh[t] - v; __syncthreads();
    int v2 = gcur_n[t]; sh[t] = v2; __syncthreads();
    for (int d = 1; d < NBUCK; d <<= 1) {
        int u = (t >= d) ? sh[t - d] : 0; __syncthreads();
        sh[t] += u; __syncthreads();
    }
    base_n[t] = sh[t] - v2;
}

// ---- Pass B: sort one bucket into its compact, block-exclusive region ----
template<int BPB, int SH, unsigned MASK, int NBINS, typename OUT>
__device__ __forceinline__ void sort_bucket(
    const unsigned* __restrict__ region, int cnt, int gbase, int b0,
    OUT* __restrict__ csr, int* __restrict__ off)
{
    __shared__ unsigned lh[512];
    __shared__ unsigned lw[4];
    const int t = threadIdx.x;
    lh[t] = 0; lh[t + 256] = 0;
    __syncthreads();
    for (int i = t; i < cnt; i += 256) {
        int bin = (int)(region[i] >> SH) - b0;
        atomicAdd(&lh[bin], 1u);
    }
    __syncthreads();
    unsigned h0 = lh[2 * t], h1 = lh[2 * t + 1];
    unsigned s = h0 + h1, inc = s;
    const int lane = t & 63;
    #pragma unroll
    for (int d = 1; d <= 32; d <<= 1) {
        unsigned v = (unsigned)__shfl_up((int)inc, d, 64);
        if (lane >= d) inc += v;
    }
    if (lane == 63) lw[t >> 6] = inc;
    __syncthreads();
    unsigned pre = 0;
    #pragma unroll
    for (int w = 0; w < 4; w++) if (w < (t >> 6)) pre += lw[w];
    unsigned excl = pre + inc - s;
    unsigned c0 = (unsigned)gbase + excl;
    unsigned c1 = c0 + h0;
    lh[2 * t] = c0; lh[2 * t + 1] = c1;
    int i0 = 2 * t, i1 = 2 * t + 1;
    if (i0 <= BPB && b0 + i0 <= NBINS) off[b0 + i0] = (int)c0;
    if (i1 <= BPB && b0 + i1 <= NBINS) off[b0 + i1] = (int)c1;
    __syncthreads();
    for (int i = t; i < cnt; i += 256) {
        unsigned ent = region[i];
        int bin = (int)(ent >> SH) - b0;
        unsigned pos = atomicAdd(&lh[bin], 1u);
        csr[pos] = (OUT)(ent & MASK);
    }
}

__global__ __launch_bounds__(256) void bucket_sort(
    const unsigned* __restrict__ buck_e, const unsigned* __restrict__ buck_n,
    const int* __restrict__ gcur_e, const int* __restrict__ gcur_n,
    const int* __restrict__ base_e, const int* __restrict__ base_n,
    unsigned* __restrict__ csr_e, unsigned short* __restrict__ csr_n,
    int* __restrict__ off_e, int* __restrict__ off_n)
{
    int b = blockIdx.x & 255;
    if (blockIdx.x < 256)
        sort_bucket<BPB_E, SH_E, 0x1FFFFu, NEDGES, unsigned>(
            buck_e + (size_t)b * CAP, gcur_e[b], base_e[b], b * BPB_E, csr_e, off_e);
    else
        sort_bucket<BPB_N, SH_N, 0x7FFFu, NNODES, unsigned short>(
            buck_n + (size_t)b * CAP, gcur_n[b], base_n[b], b * BPB_N, csr_n, off_n);
}

// ---- segmented sum over bf16 table + optional fused BN/sigmoid finalize ----
template<typename IDX>
__global__ __launch_bounds__(256) void seg_sum_fin_bf16(
    const unsigned short* __restrict__ table, const IDX* __restrict__ csr,
    const int* __restrict__ off, const float* __restrict__ x,
    const float* __restrict__ g, const float* __restrict__ bb,
    const float* __restrict__ mm, const float* __restrict__ vv,
    float* __restrict__ agg_out, float* __restrict__ fin_out, int nseg)
{
    int gid = blockIdx.x * blockDim.x + threadIdx.x;
    int seg = gid >> 5;
    if (seg >= nseg) return;
    int q = (gid & 31) * 4;
    int i0 = off[seg], i1 = off[seg + 1];
    float4 acc = make_float4(0.f, 0.f, 0.f, 0.f);
    int i = i0;
    for (; i + 3 < i1; i += 4) {
        int r0 = (int)csr[i], r1 = (int)csr[i + 1];
        int r2 = (int)csr[i + 2], r3 = (int)csr[i + 3];
        ushort4 a0 = *(const ushort4*)(table + (size_t)r0 * FDIM + q);
        ushort4 a1 = *(const ushort4*)(table + (size_t)r1 * FDIM + q);
        ushort4 a2 = *(const ushort4*)(table + (size_t)r2 * FDIM + q);
        ushort4 a3 = *(const ushort4*)(table + (size_t)r3 * FDIM + q);
        acc.x += (bf2f(a0.x) + bf2f(a1.x)) + (bf2f(a2.x) + bf2f(a3.x));
        acc.y += (bf2f(a0.y) + bf2f(a1.y)) + (bf2f(a2.y) + bf2f(a3.y));
        acc.z += (bf2f(a0.z) + bf2f(a1.z)) + (bf2f(a2.z) + bf2f(a3.z));
        acc.w += (bf2f(a0.w) + bf2f(a1.w)) + (bf2f(a2.w) + bf2f(a3.w));
    }
    for (; i < i1; i++) {
        int r = (int)csr[i];
        ushort4 a = *(const ushort4*)(table + (size_t)r * FDIM + q);
        acc.x += bf2f(a.x); acc.y += bf2f(a.y);
        acc.z += bf2f(a.z); acc.w += bf2f(a.w);
    }
    if (agg_out)
        *(float4*)(agg_out + (size_t)seg * FDIM + q) = acc;
    if (fin_out) {
        float4 xv = *(const float4*)(x + (size_t)seg * FDIM + q);
        float4 gg = *(const float4*)(g + q);
        float4 bt = *(const float4*)(bb + q);
        float4 mn = *(const float4*)(mm + q);
        float4 vr = *(const float4*)(vv + q);
        float4 o;
        o.x = sigmoidf_((xv.x - mn.x) * (gg.x * rsqrtf(vr.x + BN_EPS)) + bt.x + acc.x);
        o.y = sigmoidf_((xv.y - mn.y) * (gg.y * rsqrtf(vr.y + BN_EPS)) + bt.y + acc.y);
        o.z = sigmoidf_((xv.z - mn.z) * (gg.z * rsqrtf(vr.z + BN_EPS)) + bt.z + acc.z);
        o.w = sigmoidf_((xv.w - mn.w) * (gg.w * rsqrtf(vr.w + BN_EPS)) + bt.w + acc.w);
        *(float4*)(fin_out + (size_t)seg * FDIM + q) = o;
    }
}

extern "C" void kernel_launch(void* const* d_in, const int* in_sizes, int n_in,
                              void* d_out, int out_size, void* d_ws, size_t ws_size,
                              hipStream_t stream)
{
    const float* x0       = (const float*)d_in[0];
    const float* x1       = (const float*)d_in[1];
    const int*   node_idx = (const int*)d_in[2];
    const int*   edge_idx = (const int*)d_in[3];
    const float* W_nh     = (const float*)d_in[4];
    const float* b_nh     = (const float*)d_in[5];
    const float* W_en     = (const float*)d_in[6];
    const float* b_en     = (const float*)d_in[7];
    const float* bn0g = (const float*)d_in[8];
    const float* bn0b = (const float*)d_in[9];
    const float* bn0m = (const float*)d_in[10];
    const float* bn0v = (const float*)d_in[11];
    const float* bn1g = (const float*)d_in[12];
    const float* bn1b = (const float*)d_in[13];
    const float* bn1m = (const float*)d_in[14];
    const float* bn1v = (const float*)d_in[15];

    float* ws = (float*)d_ws;
    float* B    = ws;                           // node_msg_agg fp32 [20000,128]
    float* WTnh = B + (size_t)NEDGES * FDIM;    // [128,128]
    float* WTen = WTnh + FDIM * FDIM;           // [256,128]
    unsigned short* A_bf = (unsigned short*)(WTen + 2 * FDIM * FDIM);  // [100000,128] bf16
    unsigned short* D_bf = A_bf + (size_t)NNODES * FDIM;               // [20000,128] bf16
    int* ip    = (int*)(D_bf + (size_t)NEDGES * FDIM);
    int* off_e = ip;                    // 20001 (pad 20004)
    int* off_n = off_e + 20004;         // 100001 (pad 100004)
    unsigned* csr_e = (unsigned*)(off_n + 100004);          // 2M u32 (node ids by edge)
    unsigned short* csr_n = (unsigned short*)(csr_e + NNZ_);// 2M u16 (edge ids by node)
    unsigned* buck_e = (unsigned*)(csr_n + NNZ_);           // [NBUCK*CAP]
    unsigned* buck_n = buck_e + (size_t)NBUCK * CAP;        // [NBUCK*CAP]
    int* gcur_e = (int*)(buck_n + (size_t)NBUCK * CAP);     // 256
    int* gcur_n = gcur_e + NBUCK;                           // 256
    int* base_e = gcur_n + NBUCK;                           // 256
    int* base_n = base_e + NBUCK;                           // 256

    // --- CSR build via 2-level bucket sort (3 launches + tiny memset) ---
    hipMemsetAsync(gcur_e, 0, 2 * NBUCK * sizeof(int), stream);
    bucket_scatter<<<(NNZ_ + 4095) / 4096, 1024, 0, stream>>>(
        node_idx, edge_idx, buck_e, buck_n, gcur_e, gcur_n);
    bucket_bases<<<1, 256, 0, stream>>>(gcur_e, gcur_n, base_e, base_n);
    bucket_sort<<<2 * NBUCK, 256, 0, stream>>>(buck_e, buck_n, gcur_e, gcur_n,
                                               base_e, base_n, csr_e, csr_n,
                                               off_e, off_n);

    transpose2<<<(3 * FDIM * FDIM + 255) / 256, 256, 0, stream>>>(W_nh, W_en, WTnh, WTen);

    float* out0 = (float*)d_out;
    float* out1 = out0 + (size_t)NNODES * FDIM;

    // node -> hyperedge: GEMM1 (bf16 out) then pull-aggregate (+ fused x1_out)
    gemm_sig_bf16<128><<<NNODES / 32, 256, 0, stream>>>(x0, nullptr, WTnh, b_nh, A_bf);
    seg_sum_fin_bf16<unsigned><<<(NEDGES * 32 + 255) / 256, 256, 0, stream>>>(
        A_bf, csr_e, off_e, x1, bn1g, bn1b, bn1m, bn1v, B, out1, NEDGES);

    // hyperedge -> node: GEMM2 (bf16 out) then pull-aggregate (+ fused x0_out)
    gemm_sig_bf16<256><<<NEDGES / 32, 256, 0, stream>>>(x1, B, WTen, b_en, D_bf);
    seg_sum_fin_bf16<unsigned short><<<(NNODES * 32 + 255) / 256, 256, 0, stream>>>(
        D_bf, csr_n, off_n, x0, bn0g, bn0b, bn0m, bn0v, nullptr, out0, NNODES);
}

// Round 8
// 404.563 us; speedup vs baseline: 17.1431x; 1.0468x over previous
//
#include <hip/hip_runtime.h>
#include <hip/hip_bf16.h>
#include <math.h>

#define NNODES 100000
#define NEDGES 20000
#define NNZ_   2000000
#define FDIM   128
#define BN_EPS 1e-5f

// ---- bucket-sort geometry ----
#define NBUCK 256
#define CAP   9216        // per-bucket capacity (mean ~7812, sigma ~88 -> +16 sigma)
#define BPB_E 79          // bins/bucket, edge dir
#define BPB_N 391         // bins/bucket, node dir
#define SH_E  17          // edge entry = (e<<17)|n
#define SH_N  15          // node entry = (n<<15)|e

typedef __attribute__((ext_vector_type(8))) short bf16x8_t;
typedef __attribute__((ext_vector_type(4))) float f32x4_t;

__device__ __forceinline__ float sigmoidf_(float x) {
    return 1.0f / (1.0f + __expf(-x));
}
__device__ __forceinline__ float bf2f(unsigned short u) {
    return __uint_as_float(((unsigned)u) << 16);
}
__device__ __forceinline__ unsigned short f2bf(float f) {
    __hip_bfloat16 h = __float2bfloat16(f);   // RNE
    return *reinterpret_cast<unsigned short*>(&h);
}

// ---- prep: bf16 copy of W_nh (B-operand layout = as-is) + transpose W_en ----
__global__ __launch_bounds__(256) void prep_w(
    const float* __restrict__ W_nh, const float* __restrict__ W_en,
    unsigned short* __restrict__ Wnh_bf, float* __restrict__ WTen)
{
    int idx = blockIdx.x * blockDim.x + threadIdx.x;
    if (idx < FDIM * FDIM) {
        Wnh_bf[idx] = f2bf(W_nh[idx]);
    } else {
        int j = idx - FDIM * FDIM;
        if (j >= 2 * FDIM * FDIM) return;
        int k = j >> 7, c = j & 127;
        WTen[j] = W_en[c * 2 * FDIM + k];
    }
}

// ---- GEMM1 via MFMA: out[100000,128] = sigmoid(x0 @ W_nh^T + b), bf16 out ----
// block: 32 rows x 128 cols; 4 waves: wave&1 -> m-half(16), wave>>1 -> n-half(64)
__global__ __launch_bounds__(256) void gemm1_mfma(
    const float* __restrict__ x0, const unsigned short* __restrict__ Wb,
    const float* __restrict__ bias, unsigned short* __restrict__ out)
{
    __shared__ unsigned short As[32][FDIM + 8];   // +8 shorts: kills bank conflicts, keeps 16B align
    const int tid  = threadIdx.x;
    const int row0 = blockIdx.x * 32;
    // stage x0 tile -> bf16 LDS (each thread: 16 elems = 4 float4 loads)
    {
        int r = tid >> 3, c0 = (tid & 7) * 16;
        const float* src = x0 + (size_t)(row0 + r) * FDIM + c0;
        unsigned short* dst = &As[r][c0];
        #pragma unroll
        for (int i = 0; i < 4; i++) {
            float4 v = *(const float4*)(src + i * 4);
            dst[i * 4 + 0] = f2bf(v.x);
            dst[i * 4 + 1] = f2bf(v.y);
            dst[i * 4 + 2] = f2bf(v.z);
            dst[i * 4 + 3] = f2bf(v.w);
        }
    }
    __syncthreads();
    const int wave  = tid >> 6;
    const int lane  = tid & 63;
    const int mhalf = wave & 1;
    const int nhalf = wave >> 1;
    const int lm    = lane & 15;
    const int quad  = lane >> 4;
    f32x4_t acc[4] = {};
    #pragma unroll
    for (int ks = 0; ks < 4; ks++) {
        bf16x8_t a = *(const bf16x8_t*)&As[mhalf * 16 + lm][ks * 32 + quad * 8];
        #pragma unroll
        for (int nt = 0; nt < 4; nt++) {
            int n = nhalf * 64 + nt * 16 + lm;
            bf16x8_t b = *(const bf16x8_t*)(Wb + (size_t)n * FDIM + ks * 32 + quad * 8);
            acc[nt] = __builtin_amdgcn_mfma_f32_16x16x32_bf16(a, b, acc[nt], 0, 0, 0);
        }
    }
    // D layout: col(n)=lane&15, row(m)=quad*4+reg
    const int mbase = row0 + mhalf * 16 + quad * 4;
    #pragma unroll
    for (int nt = 0; nt < 4; nt++) {
        int n = nhalf * 64 + nt * 16 + lm;
        float bv = bias[n];
        #pragma unroll
        for (int r2 = 0; r2 < 4; r2++) {
            out[(size_t)(mbase + r2) * FDIM + n] = f2bf(sigmoidf_(acc[nt][r2] + bv));
        }
    }
}

// ---- GEMM2 (fp32 vector): out[20000,128] = sigmoid(cat(x1,B) @ W_en^T + b), bf16 out ----
__global__ __launch_bounds__(256, 2) void gemm_sig_bf16(
    const float* __restrict__ A1, const float* __restrict__ A2,
    const float* __restrict__ WT, const float* __restrict__ bias,
    unsigned short* __restrict__ out)
{
    constexpr int K = 256, BK = 64;
    __shared__ float As[32][BK + 4];
    __shared__ float Ws[BK][FDIM];
    const int tid  = threadIdx.x;
    const int row0 = blockIdx.x * 32;
    const int tcol = tid & 31;
    const int trow = tid >> 5;
    float acc[4][4] = {};
    for (int kk = 0; kk < K; kk += BK) {
        const float* Asrc = (kk < FDIM) ? A1 : A2;
        const int koff    = (kk < FDIM) ? kk : kk - FDIM;
        #pragma unroll
        for (int i = 0; i < 2; i++) {
            int l = tid + i * 256;
            int r = l >> 4, j = l & 15;
            float4 v = *(const float4*)(Asrc + (size_t)(row0 + r) * FDIM + koff + j * 4);
            *(float4*)&As[r][j * 4] = v;
        }
        #pragma unroll
        for (int i = 0; i < 8; i++) {
            int l = tid + i * 256;
            int k = l >> 5, j = l & 31;
            float4 v = *(const float4*)(WT + (size_t)(kk + k) * FDIM + j * 4);
            *(float4*)&Ws[k][j * 4] = v;
        }
        __syncthreads();
        #pragma unroll
        for (int k = 0; k < BK; k += 4) {
            float4 a[4];
            #pragma unroll
            for (int r = 0; r < 4; r++)
                a[r] = *(const float4*)&As[trow * 4 + r][k];
            #pragma unroll
            for (int kq = 0; kq < 4; kq++) {
                float4 w = *(const float4*)&Ws[k + kq][tcol * 4];
                #pragma unroll
                for (int r = 0; r < 4; r++) {
                    float av = (kq == 0) ? a[r].x : (kq == 1) ? a[r].y
                             : (kq == 2) ? a[r].z : a[r].w;
                    acc[r][0] += av * w.x;
                    acc[r][1] += av * w.y;
                    acc[r][2] += av * w.z;
                    acc[r][3] += av * w.w;
                }
            }
        }
        __syncthreads();
    }
    float4 bv = *(const float4*)(bias + tcol * 4);
    #pragma unroll
    for (int r = 0; r < 4; r++) {
        int row = row0 + trow * 4 + r;
        ushort4 o;
        o.x = f2bf(sigmoidf_(acc[r][0] + bv.x));
        o.y = f2bf(sigmoidf_(acc[r][1] + bv.y));
        o.z = f2bf(sigmoidf_(acc[r][2] + bv.z));
        o.w = f2bf(sigmoidf_(acc[r][3] + bv.w));
        *(ushort4*)(out + (size_t)row * FDIM + tcol * 4) = o;
    }
}

// ---- Pass A: coarse bucket partition (both directions in one pass) ----
__global__ __launch_bounds__(1024) void bucket_scatter(
    const int* __restrict__ ni, const int* __restrict__ ei,
    unsigned* __restrict__ buck_e, unsigned* __restrict__ buck_n,
    int* __restrict__ gcur_e, int* __restrict__ gcur_n)
{
    __shared__ int lh_e[NBUCK], lh_n[NBUCK], lb_e[NBUCK], lb_n[NBUCK];
    const int t = threadIdx.x;
    if (t < NBUCK) { lh_e[t] = 0; lh_n[t] = 0; }
    __syncthreads();
    unsigned ent_e[4], ent_n[4];
    int be[4], bn[4], re[4], rn[4];
    const int base = blockIdx.x * 4096;
    #pragma unroll
    for (int j = 0; j < 4; j++) {
        int i = base + j * 1024 + t;
        if (i < NNZ_) {
            unsigned n = (unsigned)ni[i], e = (unsigned)ei[i];
            ent_e[j] = (e << SH_E) | n;  be[j] = (int)(e / BPB_E);
            ent_n[j] = (n << SH_N) | e;  bn[j] = (int)(n / BPB_N);
            re[j] = atomicAdd(&lh_e[be[j]], 1);
            rn[j] = atomicAdd(&lh_n[bn[j]], 1);
        } else { be[j] = -1; }
    }
    __syncthreads();
    if (t < NBUCK) {
        lb_e[t] = t * CAP + atomicAdd(&gcur_e[t], lh_e[t]);
        lb_n[t] = t * CAP + atomicAdd(&gcur_n[t], lh_n[t]);
    }
    __syncthreads();
    #pragma unroll
    for (int j = 0; j < 4; j++) {
        if (be[j] >= 0) {
            buck_e[(size_t)lb_e[be[j]] + re[j]] = ent_e[j];
            buck_n[(size_t)lb_n[bn[j]] + rn[j]] = ent_n[j];
        }
    }
}

// ---- Pass B: sort one bucket into its compact region (bases inline) ----
template<int BPB, int SH, unsigned MASK, int NBINS, typename OUT>
__device__ __forceinline__ void sort_bucket(
    const unsigned* __restrict__ region, int cnt, int gbase, int b0,
    OUT* __restrict__ csr, int* __restrict__ off)
{
    __shared__ unsigned lh[512];
    __shared__ unsigned lw[4];
    const int t = threadIdx.x;
    lh[t] = 0; lh[t + 256] = 0;
    __syncthreads();
    for (int i = t; i < cnt; i += 256) {
        int bin = (int)(region[i] >> SH) - b0;
        atomicAdd(&lh[bin], 1u);
    }
    __syncthreads();
    unsigned h0 = lh[2 * t], h1 = lh[2 * t + 1];
    unsigned s = h0 + h1, inc = s;
    const int lane = t & 63;
    #pragma unroll
    for (int d = 1; d <= 32; d <<= 1) {
        unsigned v = (unsigned)__shfl_up((int)inc, d, 64);
        if (lane >= d) inc += v;
    }
    if (lane == 63) lw[t >> 6] = inc;
    __syncthreads();
    unsigned pre = 0;
    #pragma unroll
    for (int w = 0; w < 4; w++) if (w < (t >> 6)) pre += lw[w];
    unsigned excl = pre + inc - s;
    unsigned c0 = (unsigned)gbase + excl;
    unsigned c1 = c0 + h0;
    lh[2 * t] = c0; lh[2 * t + 1] = c1;
    int i0 = 2 * t, i1 = 2 * t + 1;
    if (i0 <= BPB && b0 + i0 <= NBINS) off[b0 + i0] = (int)c0;
    if (i1 <= BPB && b0 + i1 <= NBINS) off[b0 + i1] = (int)c1;
    __syncthreads();
    for (int i = t; i < cnt; i += 256) {
        unsigned ent = region[i];
        int bin = (int)(ent >> SH) - b0;
        unsigned pos = atomicAdd(&lh[bin], 1u);
        csr[pos] = (OUT)(ent & MASK);
    }
}

__global__ __launch_bounds__(256) void bucket_sort(
    const unsigned* __restrict__ buck_e, const unsigned* __restrict__ buck_n,
    const int* __restrict__ gcur_e, const int* __restrict__ gcur_n,
    unsigned* __restrict__ csr_e, unsigned short* __restrict__ csr_n,
    int* __restrict__ off_e, int* __restrict__ off_n)
{
    const int b = blockIdx.x & 255;
    const int* gc = (blockIdx.x < 256) ? gcur_e : gcur_n;
    __shared__ int ws4[4];
    const int t = threadIdx.x;
    int v = (t < b) ? gc[t] : 0;
    #pragma unroll
    for (int d = 32; d > 0; d >>= 1) v += __shfl_down(v, d, 64);
    if ((t & 63) == 0) ws4[t >> 6] = v;
    __syncthreads();
    const int gbase = ws4[0] + ws4[1] + ws4[2] + ws4[3];
    const int cnt = gc[b];
    __syncthreads();
    if (blockIdx.x < 256)
        sort_bucket<BPB_E, SH_E, 0x1FFFFu, NEDGES, unsigned>(
            buck_e + (size_t)b * CAP, cnt, gbase, b * BPB_E, csr_e, off_e);
    else
        sort_bucket<BPB_N, SH_N, 0x7FFFu, NNODES, unsigned short>(
            buck_n + (size_t)b * CAP, cnt, gbase, b * BPB_N, csr_n, off_n);
}

// ---- segmented sum over bf16 table + fused BN/sigmoid finalize ----
template<typename IDX>
__global__ __launch_bounds__(256) void seg_sum_fin_bf16(
    const unsigned short* __restrict__ table, const IDX* __restrict__ csr,
    const int* __restrict__ off, const float* __restrict__ x,
    const float* __restrict__ g, const float* __restrict__ bb,
    const float* __restrict__ mm, const float* __restrict__ vv,
    float* __restrict__ agg_out, float* __restrict__ fin_out, int nseg)
{
    int gid = blockIdx.x * blockDim.x + threadIdx.x;
    int seg = gid >> 5;
    if (seg >= nseg) return;
    int q = (gid & 31) * 4;
    int i0 = off[seg], i1 = off[seg + 1];
    float4 acc = make_float4(0.f, 0.f, 0.f, 0.f);
    int i = i0;
    for (; i + 3 < i1; i += 4) {
        int r0 = (int)csr[i], r1 = (int)csr[i + 1];
        int r2 = (int)csr[i + 2], r3 = (int)csr[i + 3];
        ushort4 a0 = *(const ushort4*)(table + (size_t)r0 * FDIM + q);
        ushort4 a1 = *(const ushort4*)(table + (size_t)r1 * FDIM + q);
        ushort4 a2 = *(const ushort4*)(table + (size_t)r2 * FDIM + q);
        ushort4 a3 = *(const ushort4*)(table + (size_t)r3 * FDIM + q);
        acc.x += (bf2f(a0.x) + bf2f(a1.x)) + (bf2f(a2.x) + bf2f(a3.x));
        acc.y += (bf2f(a0.y) + bf2f(a1.y)) + (bf2f(a2.y) + bf2f(a3.y));
        acc.z += (bf2f(a0.z) + bf2f(a1.z)) + (bf2f(a2.z) + bf2f(a3.z));
        acc.w += (bf2f(a0.w) + bf2f(a1.w)) + (bf2f(a2.w) + bf2f(a3.w));
    }
    for (; i < i1; i++) {
        int r = (int)csr[i];
        ushort4 a = *(const ushort4*)(table + (size_t)r * FDIM + q);
        acc.x += bf2f(a.x); acc.y += bf2f(a.y);
        acc.z += bf2f(a.z); acc.w += bf2f(a.w);
    }
    if (agg_out)
        *(float4*)(agg_out + (size_t)seg * FDIM + q) = acc;
    if (fin_out) {
        float4 xv = *(const float4*)(x + (size_t)seg * FDIM + q);
        float4 gg = *(const float4*)(g + q);
        float4 bt = *(const float4*)(bb + q);
        float4 mn = *(const float4*)(mm + q);
        float4 vr = *(const float4*)(vv + q);
        float4 o;
        o.x = sigmoidf_((xv.x - mn.x) * (gg.x * rsqrtf(vr.x + BN_EPS)) + bt.x + acc.x);
        o.y = sigmoidf_((xv.y - mn.y) * (gg.y * rsqrtf(vr.y + BN_EPS)) + bt.y + acc.y);
        o.z = sigmoidf_((xv.z - mn.z) * (gg.z * rsqrtf(vr.z + BN_EPS)) + bt.z + acc.z);
        o.w = sigmoidf_((xv.w - mn.w) * (gg.w * rsqrtf(vr.w + BN_EPS)) + bt.w + acc.w);
        *(float4*)(fin_out + (size_t)seg * FDIM + q) = o;
    }
}

extern "C" void kernel_launch(void* const* d_in, const int* in_sizes, int n_in,
                              void* d_out, int out_size, void* d_ws, size_t ws_size,
                              hipStream_t stream)
{
    const float* x0       = (const float*)d_in[0];
    const float* x1       = (const float*)d_in[1];
    const int*   node_idx = (const int*)d_in[2];
    const int*   edge_idx = (const int*)d_in[3];
    const float* W_nh     = (const float*)d_in[4];
    const float* b_nh     = (const float*)d_in[5];
    const float* W_en     = (const float*)d_in[6];
    const float* b_en     = (const float*)d_in[7];
    const float* bn0g = (const float*)d_in[8];
    const float* bn0b = (const float*)d_in[9];
    const float* bn0m = (const float*)d_in[10];
    const float* bn0v = (const float*)d_in[11];
    const float* bn1g = (const float*)d_in[12];
    const float* bn1b = (const float*)d_in[13];
    const float* bn1m = (const float*)d_in[14];
    const float* bn1v = (const float*)d_in[15];

    float* ws = (float*)d_ws;
    float* B    = ws;                           // node_msg_agg fp32 [20000,128]
    float* WTen = B + (size_t)NEDGES * FDIM;    // [256,128] fp32
    unsigned short* Wnh_bf = (unsigned short*)(WTen + 2 * FDIM * FDIM); // [128,128] bf16
    unsigned short* A_bf = Wnh_bf + FDIM * FDIM;                  // [100000,128] bf16
    unsigned short* D_bf = A_bf + (size_t)NNODES * FDIM;          // [20000,128] bf16
    int* ip    = (int*)(D_bf + (size_t)NEDGES * FDIM);
    int* off_e = ip;                    // 20001 (pad 20004)
    int* off_n = off_e + 20004;         // 100001 (pad 100004)
    unsigned* csr_e = (unsigned*)(off_n + 100004);          // 2M u32
    unsigned short* csr_n = (unsigned short*)(csr_e + NNZ_);// 2M u16
    unsigned* buck_e = (unsigned*)(csr_n + NNZ_);           // [NBUCK*CAP]
    unsigned* buck_n = buck_e + (size_t)NBUCK * CAP;        // [NBUCK*CAP]
    int* gcur_e = (int*)(buck_n + (size_t)NBUCK * CAP);     // 256
    int* gcur_n = gcur_e + NBUCK;                           // 256

    // --- CSR build via 2-level bucket sort ---
    hipMemsetAsync(gcur_e, 0, 2 * NBUCK * sizeof(int), stream);
    bucket_scatter<<<(NNZ_ + 4095) / 4096, 1024, 0, stream>>>(
        node_idx, edge_idx, buck_e, buck_n, gcur_e, gcur_n);
    bucket_sort<<<2 * NBUCK, 256, 0, stream>>>(buck_e, buck_n, gcur_e, gcur_n,
                                               csr_e, csr_n, off_e, off_n);

    prep_w<<<(3 * FDIM * FDIM + 255) / 256, 256, 0, stream>>>(W_nh, W_en, Wnh_bf, WTen);

    float* out0 = (float*)d_out;
    float* out1 = out0 + (size_t)NNODES * FDIM;

    // node -> hyperedge: GEMM1 (MFMA, bf16 out) then pull-aggregate (+ fused x1_out)
    gemm1_mfma<<<NNODES / 32, 256, 0, stream>>>(x0, Wnh_bf, b_nh, A_bf);
    seg_sum_fin_bf16<unsigned><<<(NEDGES * 32 + 255) / 256, 256, 0, stream>>>(
        A_bf, csr_e, off_e, x1, bn1g, bn1b, bn1m, bn1v, B, out1, NEDGES);

    // hyperedge -> node: GEMM2 (fp32 vector, bf16 out) then pull-aggregate (+ fused x0_out)
    gemm_sig_bf16<<<NEDGES / 32, 256, 0, stream>>>(x1, B, WTen, b_en, D_bf);
    seg_sum_fin_bf16<unsigned short><<<(NNODES * 32 + 255) / 256, 256, 0, stream>>>(
        D_bf, csr_n, off_n, x0, bn0g, bn0b, bn0m, bn0v, nullptr, out0, NNODES);
}